// Round 1
// baseline (3791.381 us; speedup 1.0000x reference)
//
#include <hip/hip_runtime.h>

#define EPS 1e-5f

// ---------------------------------------------------------------------------
// Generic batched "TN" GEMM: C[m][n] = sum_k A[k][m] * B[k][n]
// A: element (z,k,m) at A[z*bsA + k*lda + m]
// B: element (z,k,n) at B[z*bsB + k*ldb + n]
// C: element (z,m,n) at C[z*bsC + m*ldc + n]
// Both operands are K-major -> tile loads are fully coalesced (no transpose
// in the loader). Requires M%BM==0, N%BN==0, K%BK==0, all lds %4==0.
// ---------------------------------------------------------------------------
template<int BM, int BN, int BK>
__global__ __launch_bounds__((BM/8)*(BN/8))
void gemm_tn(const float* __restrict__ A, const float* __restrict__ B,
             float* __restrict__ C, int M, int N, int K,
             int lda, int ldb, int ldc,
             long long bsA, long long bsB, long long bsC)
{
    constexpr int T = (BM/8)*(BN/8);
    __shared__ float As[BK][BM];
    __shared__ float Bs[BK][BN];
    const int tid = threadIdx.x;
    const int n0 = blockIdx.x * BN;
    const int m0 = blockIdx.y * BM;
    A += blockIdx.z * bsA;
    B += blockIdx.z * bsB;
    C += blockIdx.z * bsC;

    const int tx = tid % (BN/8);
    const int ty = tid / (BN/8);

    float acc[8][8];
#pragma unroll
    for (int u = 0; u < 8; u++)
#pragma unroll
        for (int v = 0; v < 8; v++) acc[u][v] = 0.f;

    for (int k0 = 0; k0 < K; k0 += BK) {
#pragma unroll
        for (int idx = tid * 4; idx < BK * BM; idx += T * 4) {
            int r = idx / BM, c = idx % BM;
            *(float4*)&As[r][c] = *(const float4*)(A + (long long)(k0 + r) * lda + m0 + c);
        }
#pragma unroll
        for (int idx = tid * 4; idx < BK * BN; idx += T * 4) {
            int r = idx / BN, c = idx % BN;
            *(float4*)&Bs[r][c] = *(const float4*)(B + (long long)(k0 + r) * ldb + n0 + c);
        }
        __syncthreads();
#pragma unroll
        for (int kk = 0; kk < BK; kk++) {
            float a[8], b[8];
            *(float4*)&a[0] = *(float4*)&As[kk][ty * 4];
            *(float4*)&a[4] = *(float4*)&As[kk][BM / 2 + ty * 4];
            *(float4*)&b[0] = *(float4*)&Bs[kk][tx * 4];
            *(float4*)&b[4] = *(float4*)&Bs[kk][BN / 2 + tx * 4];
#pragma unroll
            for (int u = 0; u < 8; u++)
#pragma unroll
                for (int v = 0; v < 8; v++)
                    acc[u][v] += a[u] * b[v];
        }
        __syncthreads();
    }

#pragma unroll
    for (int u = 0; u < 8; u++) {
        int row = m0 + (u < 4 ? ty * 4 + u : BM / 2 + ty * 4 + (u - 4));
        float4 lo = make_float4(acc[u][0], acc[u][1], acc[u][2], acc[u][3]);
        float4 hi = make_float4(acc[u][4], acc[u][5], acc[u][6], acc[u][7]);
        *(float4*)(C + (long long)row * ldc + n0 + tx * 4) = lo;
        *(float4*)(C + (long long)row * ldc + n0 + BN / 2 + tx * 4) = hi;
    }
}

// ---------------------------------------------------------------------------
// 64x64 LDS tile transpose: out[(c0+q)*ldout + r0+p] = in[(r0+p)*ldin + c0+q]
// Requires rows%64==0, cols%64==0. grid = (cols/64, rows/64, batches)
// ---------------------------------------------------------------------------
__global__ __launch_bounds__(256)
void transpose_k(const float* __restrict__ in, float* __restrict__ out,
                 int rows, int cols, int ldin, int ldout,
                 long long bsIn, long long bsOut)
{
    __shared__ float t[64][65];
    in += blockIdx.z * bsIn;
    out += blockIdx.z * bsOut;
    const int c0 = blockIdx.x * 64, r0 = blockIdx.y * 64;
    const int c = threadIdx.x & 63, r4 = threadIdx.x >> 6;
#pragma unroll
    for (int rr = r4; rr < 64; rr += 4)
        t[rr][c] = in[(long long)(r0 + rr) * ldin + c0 + c];
    __syncthreads();
#pragma unroll
    for (int rr = r4; rr < 64; rr += 4)
        out[(long long)(c0 + rr) * ldout + r0 + c] = t[c][rr];
}

// ---------------------------------------------------------------------------
// Per-b sum / sumsq over the 512x4096 scores plane. grid=(64, 8), block=256.
// stats[b*2] += sum, stats[b*2+1] += sumsq  (stats pre-zeroed via memset)
// ---------------------------------------------------------------------------
__global__ __launch_bounds__(256)
void stats_k(const float* __restrict__ S, float* __restrict__ stats)
{
    const int b = blockIdx.y;
    const float4* p = (const float4*)(S + (long long)b * 2097152 +
                                      (long long)blockIdx.x * 32768);
    float s = 0.f, s2 = 0.f;
    for (int i = threadIdx.x; i < 8192; i += 256) {
        float4 v = p[i];
        s  += v.x + v.y + v.z + v.w;
        s2 += v.x * v.x + v.y * v.y + v.z * v.z + v.w * v.w;
    }
    __shared__ float rs[4], rs2[4];
    const int lane = threadIdx.x & 63, w = threadIdx.x >> 6;
#pragma unroll
    for (int off = 32; off; off >>= 1) {
        s  += __shfl_down(s, off, 64);
        s2 += __shfl_down(s2, off, 64);
    }
    if (lane == 0) { rs[w] = s; rs2[w] = s2; }
    __syncthreads();
    if (threadIdx.x == 0) {
        atomicAdd(&stats[b * 2],     rs[0] + rs[1] + rs[2] + rs[3]);
        atomicAdd(&stats[b * 2 + 1], rs2[0] + rs2[1] + rs2[2] + rs2[3]);
    }
}

// ---------------------------------------------------------------------------
// Fused InstanceNorm-scale + softmax, in place on one 4096-wide row.
// softmax((s-mu)*r) == softmax(r*(s - rowmax)) since the mu shift cancels.
// grid = 8*512 rows, block = 256 (16 elements/thread held in registers).
// ---------------------------------------------------------------------------
__global__ __launch_bounds__(256)
void softmax_k(float* __restrict__ S, const float* __restrict__ stats)
{
    const int row = blockIdx.x;
    const int b = row >> 9;
    float4* p = (float4*)(S + (long long)row * 4096);

    const float inv = 1.f / 2097152.f;
    const float mu  = stats[b * 2] * inv;
    const float var = stats[b * 2 + 1] * inv - mu * mu;
    const float r   = rsqrtf(var + EPS);

    float4 v[4];
    float mx = -3.4e38f;
#pragma unroll
    for (int t = 0; t < 4; t++) {
        v[t] = p[threadIdx.x + t * 256];
        mx = fmaxf(mx, fmaxf(fmaxf(v[t].x, v[t].y), fmaxf(v[t].z, v[t].w)));
    }
    __shared__ float redm[4], reds[4];
    const int lane = threadIdx.x & 63, w = threadIdx.x >> 6;
#pragma unroll
    for (int off = 32; off; off >>= 1) mx = fmaxf(mx, __shfl_down(mx, off, 64));
    if (lane == 0) redm[w] = mx;
    __syncthreads();
    mx = fmaxf(fmaxf(redm[0], redm[1]), fmaxf(redm[2], redm[3]));

    float se = 0.f;
#pragma unroll
    for (int t = 0; t < 4; t++) {
        v[t].x = expf(r * (v[t].x - mx));
        v[t].y = expf(r * (v[t].y - mx));
        v[t].z = expf(r * (v[t].z - mx));
        v[t].w = expf(r * (v[t].w - mx));
        se += v[t].x + v[t].y + v[t].z + v[t].w;
    }
#pragma unroll
    for (int off = 32; off; off >>= 1) se += __shfl_down(se, off, 64);
    if (lane == 0) reds[w] = se;
    __syncthreads();
    const float inv_se = 1.f / (reds[0] + reds[1] + reds[2] + reds[3]);
#pragma unroll
    for (int t = 0; t < 4; t++) {
        v[t].x *= inv_se; v[t].y *= inv_se; v[t].z *= inv_se; v[t].w *= inv_se;
        p[threadIdx.x + t * 256] = v[t];
    }
}

// ---------------------------------------------------------------------------
// Orchestration.
// Shapes: emb [16][2048][64], Wq/Wk/Wv [64][512], Wo [512][64].
// dir 0: q=emb[0:8],  kv=emb[8:16], out rows [0:8)   (out_l2u)
// dir 1: q=emb[8:16], kv=emb[0:8],  out rows [8:16)  (out_u2l)
//
// Workspace (floats), ~176 MB peak with aliasing:
//   XtL   @ 0         64 x 16384
//   XtU   @ 1048576   64 x 16384
//   Q     @ 2097152   16384 x 512          (dead after S gemm)
//   Kc    @ 10485760  2048 x 4096          (dead after S gemm)
//   Vt    @ 18874368  4096 x 2048
//   S     @ 27262976  8 x 512 x 4096       (attn in place; dead after transpose)
//   attnT = Q region  8 x 4096 x 512       (aliases Q+Kc, exactly fits)
//   ctxT  = S region  8 x 512 x 2048       (aliases S)
//   stats @ 44040192  16 floats
// ---------------------------------------------------------------------------
extern "C" void kernel_launch(void* const* d_in, const int* in_sizes, int n_in,
                              void* d_out, int out_size, void* d_ws, size_t ws_size,
                              hipStream_t stream)
{
    const float* emb = (const float*)d_in[0];
    const float* Wq  = (const float*)d_in[1];
    const float* Wk  = (const float*)d_in[2];
    const float* Wv  = (const float*)d_in[3];
    const float* Wo  = (const float*)d_in[4];
    float* out = (float*)d_out;
    float* ws  = (float*)d_ws;

    float* XtL   = ws;
    float* XtU   = ws + 1048576;
    float* Q     = ws + 2097152;
    float* Kc    = ws + 10485760;
    float* Vt    = ws + 18874368;
    float* S     = ws + 27262976;
    float* attnT = Q;   // aliases Q+Kc (both dead by then)
    float* ctxT  = S;   // aliases S (dead by then)
    float* stats = ws + 44040192;

    // emb -> Xt (once; both halves)
    transpose_k<<<dim3(1, 32, 8), 256, 0, stream>>>(emb,           XtL, 2048, 64, 64, 16384, 131072LL, 2048LL);
    transpose_k<<<dim3(1, 32, 8), 256, 0, stream>>>(emb + 1048576, XtU, 2048, 64, 64, 16384, 131072LL, 2048LL);

    for (int d = 0; d < 2; d++) {
        const float* Xq = d ? XtU : XtL;
        const float* Xk = d ? XtL : XtU;

        // Q[b*2048+n][i] = sum_c Xq[c][b*2048+n] * Wq[c][i]
        gemm_tn<128, 128, 16><<<dim3(4, 128, 1), 256, 0, stream>>>(
            Xq, Wq, Q, 16384, 512, 64, 16384, 512, 512, 0, 0, 0);
        // Kc[n][b*512+ch] = sum_c Xk[c][b*2048+n] * Wk[c][ch]   (batched over b)
        gemm_tn<128, 128, 16><<<dim3(4, 16, 8), 256, 0, stream>>>(
            Xk, Wk, Kc, 2048, 512, 64, 16384, 512, 4096, 2048, 0, 512);
        // Vt[b*512+ch][n] = sum_c Wv[c][ch] * Xk[c][b*2048+n]
        gemm_tn<128, 128, 16><<<dim3(16, 4, 8), 256, 0, stream>>>(
            Wv, Xk, Vt, 512, 2048, 64, 512, 16384, 2048, 0, 2048, 1048576);
        // S[b][i][j] = sum_n Q[b*2048+n][i] * Kc[n][j]
        gemm_tn<128, 128, 16><<<dim3(32, 4, 8), 256, 0, stream>>>(
            Q, Kc, S, 512, 4096, 2048, 512, 4096, 4096, 1048576, 0, 2097152);

        hipMemsetAsync(stats, 0, 16 * sizeof(float), stream);
        stats_k<<<dim3(64, 8), 256, 0, stream>>>(S, stats);
        softmax_k<<<4096, 256, 0, stream>>>(S, stats);

        // attn -> attnT  (8 batches of [512x4096] -> [4096x512])
        transpose_k<<<dim3(64, 8, 8), 256, 0, stream>>>(
            S, attnT, 512, 4096, 4096, 512, 2097152LL, 2097152LL);

        // ctxT[b][i][n] = sum_j attnT[b][j][i] * Vt[j][n]
        gemm_tn<128, 128, 16><<<dim3(16, 4, 8), 256, 0, stream>>>(
            attnT, Vt, ctxT, 512, 2048, 4096, 512, 2048, 2048, 2097152, 0, 1048576);
        // out[b][n][c] = sum_i ctxT[b][i][n] * Wo[i][c]
        gemm_tn<64, 64, 16><<<dim3(1, 32, 8), 64, 0, stream>>>(
            ctxT, Wo, out + (long long)d * 1048576, 2048, 64, 512, 2048, 64, 64,
            1048576, 0, 131072);
    }
}

// Round 2
// 1019.513 us; speedup vs baseline: 3.7188x; 3.7188x over previous
//
#include <hip/hip_runtime.h>

#define EPS 1e-5f

// ---------------------------------------------------------------------------
// Generalized batched TN GEMM: C[m][n] = sum_k A[k][m] * B[k][n]
// Batch (blockIdx.z = z) offsets use div/mod indexing:
//   offX = (z / zNX) * bsXd + (z % zNX) * bsXm
// Split-K: grid.y = mtiles*KS; block handles K-chunk ks=blockIdx.y%KS and
// accumulates into C with atomicAdd (C must be pre-zeroed).
// STATS: fused sum/sumsq epilogue -> atomicAdd(stats[2*(z/zNC)]) for
// InstanceNorm (valid when KS==1 so each element is produced once).
// Requires M%BM==0, N%BN==0, (K/KS)%BK==0, lds %4==0.
// ---------------------------------------------------------------------------
template<int BM, int BN, int BK, int KS, bool STATS>
__global__ __launch_bounds__((BM/8)*(BN/8))
void gemm_tn(const float* __restrict__ A, const float* __restrict__ B,
             float* __restrict__ C, int M, int N, int K,
             int lda, int ldb, int ldc,
             int zNA, long long bsAd, long long bsAm,
             int zNB, long long bsBd, long long bsBm,
             int zNC, long long bsCd, long long bsCm,
             float* __restrict__ stats)
{
    constexpr int T  = (BM/8)*(BN/8);
    constexpr int NW = (T + 63) / 64;
    __shared__ float As[BK][BM];
    __shared__ float Bs[BK][BN];
    __shared__ float rs[NW], rs2[NW];

    const int tid = threadIdx.x;
    const int z = blockIdx.z;
    const int mtile = blockIdx.y / KS;
    const int ks = blockIdx.y % KS;
    const int n0 = blockIdx.x * BN;
    const int m0 = mtile * BM;
    A += (long long)(z / zNA) * bsAd + (long long)(z % zNA) * bsAm;
    B += (long long)(z / zNB) * bsBd + (long long)(z % zNB) * bsBm;
    C += (long long)(z / zNC) * bsCd + (long long)(z % zNC) * bsCm;

    const int tx = tid % (BN/8);
    const int ty = tid / (BN/8);

    float acc[8][8] = {};

    const int kc = K / KS;
    const int kBeg = ks * kc;
    for (int k0 = kBeg; k0 < kBeg + kc; k0 += BK) {
#pragma unroll
        for (int idx = tid * 4; idx < BK * BM; idx += T * 4) {
            int r = idx / BM, c = idx % BM;
            *(float4*)&As[r][c] = *(const float4*)(A + (long long)(k0 + r) * lda + m0 + c);
        }
#pragma unroll
        for (int idx = tid * 4; idx < BK * BN; idx += T * 4) {
            int r = idx / BN, c = idx % BN;
            *(float4*)&Bs[r][c] = *(const float4*)(B + (long long)(k0 + r) * ldb + n0 + c);
        }
        __syncthreads();
#pragma unroll
        for (int kk = 0; kk < BK; kk++) {
            float a[8], b[8];
            *(float4*)&a[0] = *(float4*)&As[kk][ty * 4];
            *(float4*)&a[4] = *(float4*)&As[kk][BM / 2 + ty * 4];
            *(float4*)&b[0] = *(float4*)&Bs[kk][tx * 4];
            *(float4*)&b[4] = *(float4*)&Bs[kk][BN / 2 + tx * 4];
#pragma unroll
            for (int u = 0; u < 8; u++)
#pragma unroll
                for (int v = 0; v < 8; v++)
                    acc[u][v] += a[u] * b[v];
        }
        __syncthreads();
    }

    if (KS > 1) {
#pragma unroll
        for (int u = 0; u < 8; u++) {
            int row = m0 + (u < 4 ? ty * 4 + u : BM / 2 + ty * 4 + (u - 4));
#pragma unroll
            for (int v = 0; v < 8; v++) {
                int col = n0 + (v < 4 ? tx * 4 + v : BN / 2 + tx * 4 + (v - 4));
                atomicAdd(&C[(long long)row * ldc + col], acc[u][v]);
            }
        }
    } else {
#pragma unroll
        for (int u = 0; u < 8; u++) {
            int row = m0 + (u < 4 ? ty * 4 + u : BM / 2 + ty * 4 + (u - 4));
            float4 lo = make_float4(acc[u][0], acc[u][1], acc[u][2], acc[u][3]);
            float4 hi = make_float4(acc[u][4], acc[u][5], acc[u][6], acc[u][7]);
            *(float4*)(C + (long long)row * ldc + n0 + tx * 4) = lo;
            *(float4*)(C + (long long)row * ldc + n0 + BN / 2 + tx * 4) = hi;
        }
    }

    if (STATS) {
        float s = 0.f, s2 = 0.f;
#pragma unroll
        for (int u = 0; u < 8; u++)
#pragma unroll
            for (int v = 0; v < 8; v++) { s += acc[u][v]; s2 += acc[u][v] * acc[u][v]; }
        const int lane = tid & 63, w = tid >> 6;
#pragma unroll
        for (int off = 32; off; off >>= 1) {
            s  += __shfl_down(s, off, 64);
            s2 += __shfl_down(s2, off, 64);
        }
        if (lane == 0) { rs[w] = s; rs2[w] = s2; }
        __syncthreads();
        if (tid == 0) {
            float ts = 0.f, ts2 = 0.f;
            for (int i = 0; i < NW; i++) { ts += rs[i]; ts2 += rs2[i]; }
            atomicAdd(&stats[(z / zNC) * 2], ts);
            atomicAdd(&stats[(z / zNC) * 2 + 1], ts2);
        }
    }
}

// ---------------------------------------------------------------------------
// 64x64 LDS tile transpose: out[(c0+q)*ldout + r0+p] = in[(r0+p)*ldin + c0+q]
// ---------------------------------------------------------------------------
__global__ __launch_bounds__(256)
void transpose_k(const float* __restrict__ in, float* __restrict__ out,
                 int rows, int cols, int ldin, int ldout,
                 long long bsIn, long long bsOut)
{
    __shared__ float t[64][65];
    in += blockIdx.z * bsIn;
    out += blockIdx.z * bsOut;
    const int c0 = blockIdx.x * 64, r0 = blockIdx.y * 64;
    const int c = threadIdx.x & 63, r4 = threadIdx.x >> 6;
#pragma unroll
    for (int rr = r4; rr < 64; rr += 4)
        t[rr][c] = in[(long long)(r0 + rr) * ldin + c0 + c];
    __syncthreads();
#pragma unroll
    for (int rr = r4; rr < 64; rr += 4)
        out[(long long)(c0 + rr) * ldout + r0 + c] = t[c][rr];
}

// ---------------------------------------------------------------------------
// Fused InstanceNorm-scale + softmax, in place on one 4096-wide row.
// softmax((s-mu)*r) == softmax(r*(s - rowmax)): the mu shift cancels.
// ---------------------------------------------------------------------------
__global__ __launch_bounds__(256)
void softmax_k(float* __restrict__ S, const float* __restrict__ stats)
{
    const int row = blockIdx.x;
    const int b = row >> 9;
    float4* p = (float4*)(S + (long long)row * 4096);

    const float inv = 1.f / 2097152.f;
    const float mu  = stats[b * 2] * inv;
    const float var = stats[b * 2 + 1] * inv - mu * mu;
    const float r   = rsqrtf(var + EPS);

    float4 v[4];
    float mx = -3.4e38f;
#pragma unroll
    for (int t = 0; t < 4; t++) {
        v[t] = p[threadIdx.x + t * 256];
        mx = fmaxf(mx, fmaxf(fmaxf(v[t].x, v[t].y), fmaxf(v[t].z, v[t].w)));
    }
    __shared__ float redm[4], reds[4];
    const int lane = threadIdx.x & 63, w = threadIdx.x >> 6;
#pragma unroll
    for (int off = 32; off; off >>= 1) mx = fmaxf(mx, __shfl_down(mx, off, 64));
    if (lane == 0) redm[w] = mx;
    __syncthreads();
    mx = fmaxf(fmaxf(redm[0], redm[1]), fmaxf(redm[2], redm[3]));

    float se = 0.f;
#pragma unroll
    for (int t = 0; t < 4; t++) {
        v[t].x = expf(r * (v[t].x - mx));
        v[t].y = expf(r * (v[t].y - mx));
        v[t].z = expf(r * (v[t].z - mx));
        v[t].w = expf(r * (v[t].w - mx));
        se += v[t].x + v[t].y + v[t].z + v[t].w;
    }
#pragma unroll
    for (int off = 32; off; off >>= 1) se += __shfl_down(se, off, 64);
    if (lane == 0) reds[w] = se;
    __syncthreads();
    const float inv_se = 1.f / (reds[0] + reds[1] + reds[2] + reds[3]);
#pragma unroll
    for (int t = 0; t < 4; t++) {
        v[t].x *= inv_se; v[t].y *= inv_se; v[t].z *= inv_se; v[t].w *= inv_se;
        p[threadIdx.x + t * 256] = v[t];
    }
}

// ---------------------------------------------------------------------------
// Rank-64 factorization of the whole op:
//   G[b,b']   = Xq_b^T Xkv_b'                      [64x64]   (split-K atomic)
//   E_T[b,b'] = G^T Wq                             [64x512]
//   S[b]      = concat_b' (E_T^T Wk) -> IN stats fused        [512x4096]
//   attn      = softmax(r*(S - rowmax))            in place
//   U2[b]     = attn_b^T Wo                        [4096x64] (split-K atomic)
//   Z[b,b']   = Wv U2-block                        [64x64]   (split-K atomic)
//   out_b     = sum_b' X_b' Z[b,b'] = XT2^T Zstack [2048x64] (split-K atomic)
// Everything is the TN kernel; Wv and X are pre-transposed once.
//
// Workspace (floats):
//   WvT  @ 0         512x64
//   XT2L @ 32768     512x2048   (row b'*64+c = X_lower_b'[:,c])
//   XT2U @ 1081344   512x2048
//   E_T  @ 2129920   64p x 64 x 512
//   S    @ 4227072   8 x 512 x 4096
//   ---- zeroed block per direction ----
//   G    @ 21004288  64p x 64 x 64
//   U2   @ 21266432  8 x 4096 x 64
//   Zst  @ 23363584  8 x 512 x 64
//   stats@ 23625728  16
// ---------------------------------------------------------------------------
extern "C" void kernel_launch(void* const* d_in, const int* in_sizes, int n_in,
                              void* d_out, int out_size, void* d_ws, size_t ws_size,
                              hipStream_t stream)
{
    const float* emb = (const float*)d_in[0];
    const float* Wq  = (const float*)d_in[1];
    const float* Wk  = (const float*)d_in[2];
    const float* Wv  = (const float*)d_in[3];
    const float* Wo  = (const float*)d_in[4];
    float* out = (float*)d_out;
    float* ws  = (float*)d_ws;

    const float* embL = emb;
    const float* embU = emb + 1048576;

    float* WvT   = ws;
    float* XT2L  = ws + 32768;
    float* XT2U  = ws + 1081344;
    float* E_T   = ws + 2129920;
    float* S     = ws + 4227072;
    float* G     = ws + 21004288;
    float* U2    = ws + 21266432;
    float* Zst   = ws + 23363584;
    float* stats = ws + 23625728;

    transpose_k<<<dim3(8, 1, 1), 256, 0, stream>>>(Wv, WvT, 64, 512, 512, 64, 0, 0);
    transpose_k<<<dim3(1, 32, 8), 256, 0, stream>>>(embL, XT2L, 2048, 64, 64, 2048, 131072LL, 131072LL);
    transpose_k<<<dim3(1, 32, 8), 256, 0, stream>>>(embU, XT2U, 2048, 64, 64, 2048, 131072LL, 131072LL);
    hipMemsetAsync(out, 0, (size_t)out_size * sizeof(float), stream);

    for (int d = 0; d < 2; d++) {
        const float* Xq   = d ? embU : embL;   // d=0: l2u (q=lower)
        const float* Xkv  = d ? embL : embU;
        const float* XT2k = d ? XT2L : XT2U;

        // zero G + U2 + Zst + stats in one shot
        hipMemsetAsync(G, 0, 2621456 * sizeof(float), stream);

        // G[b,b'] = Xq_b^T @ Xkv_b'   M=64 N=64 K=2048, split-K 16
        gemm_tn<64, 64, 16, 16, false><<<dim3(1, 16, 64), 64, 0, stream>>>(
            Xq, Xkv, G, 64, 64, 2048, 64, 64, 64,
            8, 131072LL, 0LL,  8, 0LL, 131072LL,  1, 4096LL, 0LL, nullptr);

        // E_T[pair] = G^T @ Wq   M=64 N=512 K=64
        gemm_tn<64, 64, 16, 1, false><<<dim3(8, 1, 64), 64, 0, stream>>>(
            G, Wq, E_T, 64, 512, 64, 64, 512, 512,
            1, 4096LL, 0LL,  1, 0LL, 0LL,  1, 32768LL, 0LL, nullptr);

        // S block = E_T^T @ Wk  -> S[b][i][b'*512+ch], fused IN stats
        gemm_tn<128, 128, 16, 1, true><<<dim3(4, 4, 64), 256, 0, stream>>>(
            E_T, Wk, S, 512, 512, 64, 512, 512, 4096,
            1, 32768LL, 0LL,  1, 0LL, 0LL,  8, 2097152LL, 512LL, stats);

        softmax_k<<<4096, 256, 0, stream>>>(S, stats);

        // U2[b] = attn_b^T @ Wo   M=4096 N=64 K=512, split-K 4
        gemm_tn<128, 64, 16, 4, false><<<dim3(1, 128, 8), 128, 0, stream>>>(
            S, Wo, U2, 4096, 64, 512, 4096, 64, 64,
            1, 2097152LL, 0LL,  1, 0LL, 0LL,  1, 262144LL, 0LL, nullptr);

        // Z[b,b'] = WvT^T @ U2-block   M=64 N=64 K=512, split-K 8
        gemm_tn<64, 64, 16, 8, false><<<dim3(1, 8, 64), 64, 0, stream>>>(
            WvT, U2, Zst, 64, 64, 512, 64, 64, 64,
            1, 0LL, 0LL,  8, 262144LL, 32768LL,  8, 32768LL, 4096LL, nullptr);

        // out_b = XT2kv^T @ Zstack_b   M=2048 N=64 K=512, split-K 4
        gemm_tn<128, 64, 16, 4, false><<<dim3(1, 64, 8), 128, 0, stream>>>(
            XT2k, Zst, out + (long long)d * 1048576, 2048, 64, 512, 2048, 64, 64,
            1, 0LL, 0LL,  1, 32768LL, 0LL,  1, 131072LL, 0LL, nullptr);
    }
}

// Round 3
// 774.187 us; speedup vs baseline: 4.8972x; 1.3169x over previous
//
#include <hip/hip_runtime.h>

#define EPS 1e-5f

// ---------------------------------------------------------------------------
// Generalized batched TN GEMM: C[m][n] = sum_k A[k][m] * B[k][n]
// Offsets per z = blockIdx.z:  off = (z/div)*bsd + (z%mod)*bsm
// KS>1: split-K, atomicAdd into pre-zeroed C. grid.y = Mtiles*KS.
// EXPSM: epilogue writes exp(r*acc) and atomicAdds per-row sums into
//        rsPtr[(z/rDiv)*512 + row] (rs pre-zeroed). Requires BN/TN==16.
// BSCALE: B rows scaled by 1/sPtr[z*sStride + k] at LDS staging.
// Micro-tile TMxTN split-half layout; requires BM%TM==0 etc., K%(KS*BK)==0.
// ---------------------------------------------------------------------------
template<int BM, int BN, int BK, int TM, int TN, int KS, bool EXPSM, bool BSCALE>
__global__ __launch_bounds__((BM/TM)*(BN/TN))
void gemm_tn(const float* __restrict__ A, const float* __restrict__ B,
             float* __restrict__ C, int K,
             int lda, int ldb, int ldc,
             int divA, long long bsAd, int modA, long long bsAm,
             int divB, long long bsBd, int modB, long long bsBm,
             int divC, long long bsCd, int modC, long long bsCm,
             const float* __restrict__ rPtr, int rDiv, float* __restrict__ rsPtr,
             const float* __restrict__ sPtr, int sStride)
{
    constexpr int T  = (BM/TM)*(BN/TN);
    constexpr int HM = TM/2, HN = TN/2;
    __shared__ float As[BK][BM];
    __shared__ float Bs[BK][BN];

    const int tid = threadIdx.x;
    const int z = blockIdx.z;
    const int mtile = blockIdx.y / KS;
    const int ks = blockIdx.y % KS;
    const int n0 = blockIdx.x * BN;
    const int m0 = mtile * BM;
    A += (long long)(z / divA) * bsAd + (long long)(z % modA) * bsAm;
    B += (long long)(z / divB) * bsBd + (long long)(z % modB) * bsBm;
    C += (long long)(z / divC) * bsCd + (long long)(z % modC) * bsCm;

    const int tx = tid % (BN/TN);
    const int ty = tid / (BN/TN);

    float acc[TM][TN] = {};

    const int kc = K / KS;
    const int kBeg = ks * kc;
    const long long sOff = BSCALE ? (long long)z * sStride : 0;

    for (int k0 = kBeg; k0 < kBeg + kc; k0 += BK) {
#pragma unroll
        for (int idx = tid * 4; idx < BK * BM; idx += T * 4) {
            int rr = idx / BM, cc = idx % BM;
            *(float4*)&As[rr][cc] = *(const float4*)(A + (long long)(k0 + rr) * lda + m0 + cc);
        }
#pragma unroll
        for (int idx = tid * 4; idx < BK * BN; idx += T * 4) {
            int rr = idx / BN, cc = idx % BN;
            float4 bv = *(const float4*)(B + (long long)(k0 + rr) * ldb + n0 + cc);
            if (BSCALE) {
                float inv = 1.0f / sPtr[sOff + k0 + rr];
                bv.x *= inv; bv.y *= inv; bv.z *= inv; bv.w *= inv;
            }
            *(float4*)&Bs[rr][cc] = bv;
        }
        __syncthreads();
#pragma unroll
        for (int kk = 0; kk < BK; kk++) {
            float a[TM], b[TN];
#pragma unroll
            for (int u = 0; u < HM; u++) {
                a[u]      = As[kk][ty * HM + u];
                a[HM + u] = As[kk][BM / 2 + ty * HM + u];
            }
#pragma unroll
            for (int v = 0; v < HN; v++) {
                b[v]      = Bs[kk][tx * HN + v];
                b[HN + v] = Bs[kk][BN / 2 + tx * HN + v];
            }
#pragma unroll
            for (int u = 0; u < TM; u++)
#pragma unroll
                for (int v = 0; v < TN; v++)
                    acc[u][v] += a[u] * b[v];
        }
        __syncthreads();
    }

    if (EXPSM) {
        const float rv = rPtr[z / rDiv];
        const long long rsBase = (long long)(z / rDiv) * 512 + m0;
#pragma unroll
        for (int u = 0; u < TM; u++) {
            int rl = (u < HM) ? ty * HM + u : BM / 2 + ty * HM + (u - HM);
            float ev[TN];
            float p = 0.f;
#pragma unroll
            for (int v = 0; v < TN; v++) { ev[v] = __expf(rv * acc[u][v]); p += ev[v]; }
            float* cr = C + (long long)(m0 + rl) * ldc + n0;
            if (HN == 4) {
                *(float4*)(cr + tx * HN) = make_float4(ev[0], ev[1], ev[2], ev[3]);
                *(float4*)(cr + BN / 2 + tx * HN) = make_float4(ev[4], ev[5], ev[6], ev[7]);
            }
#pragma unroll
            for (int off = 8; off; off >>= 1) p += __shfl_down(p, off, 16);
            if (tx == 0) atomicAdd(&rsPtr[rsBase + rl], p);
        }
    } else if (KS > 1) {
#pragma unroll
        for (int u = 0; u < TM; u++) {
            int rl = (u < HM) ? ty * HM + u : BM / 2 + ty * HM + (u - HM);
#pragma unroll
            for (int v = 0; v < TN; v++) {
                int cl = (v < HN) ? tx * HN + v : BN / 2 + tx * HN + (v - HN);
                atomicAdd(&C[(long long)(m0 + rl) * ldc + n0 + cl], acc[u][v]);
            }
        }
    } else {
#pragma unroll
        for (int u = 0; u < TM; u++) {
            int rl = (u < HM) ? ty * HM + u : BM / 2 + ty * HM + (u - HM);
            float* cr = C + (long long)(m0 + rl) * ldc + n0;
            if (HN == 4) {
                *(float4*)(cr + tx * HN) = make_float4(acc[u][0], acc[u][1], acc[u][2], acc[u][3]);
                *(float4*)(cr + BN / 2 + tx * HN) = make_float4(acc[u][4], acc[u][5], acc[u][6], acc[u][7]);
            } else if (HN == 2) {
                *(float2*)(cr + tx * HN) = make_float2(acc[u][0], acc[u][1]);
                *(float2*)(cr + BN / 2 + tx * HN) = make_float2(acc[u][2], acc[u][3]);
            } else {
#pragma unroll
                for (int v = 0; v < HN; v++) {
                    cr[tx * HN + v] = acc[u][v];
                    cr[BN / 2 + tx * HN + v] = acc[u][HN + v];
                }
            }
        }
    }
}

// ---------------------------------------------------------------------------
// 64x64 LDS tile transpose
// ---------------------------------------------------------------------------
__global__ __launch_bounds__(256)
void transpose_k(const float* __restrict__ in, float* __restrict__ out,
                 int rows, int cols, int ldin, int ldout,
                 long long bsIn, long long bsOut)
{
    __shared__ float t[64][65];
    in += blockIdx.z * bsIn;
    out += blockIdx.z * bsOut;
    const int c0 = blockIdx.x * 64, r0 = blockIdx.y * 64;
    const int c = threadIdx.x & 63, r4 = threadIdx.x >> 6;
#pragma unroll
    for (int rr = r4; rr < 64; rr += 4)
        t[rr][c] = in[(long long)(r0 + rr) * ldin + c0 + c];
    __syncthreads();
#pragma unroll
    for (int rr = r4; rr < 64; rr += 4)
        out[(long long)(c0 + rr) * ldout + r0 + c] = t[c][rr];
}

// ---------------------------------------------------------------------------
// Analytic InstanceNorm stats per (d,b):
//   sum   = sum_{b'} sum_{c'} (sum_i E[pair][i][c']) * (sum_ch Wk[c'][ch])
//   sumsq = sum_{b'} <GE[pair], GW>
//   rOut[z] = rsqrt(var + EPS),  var = sumsq/P - (sum/P)^2,  P = 512*4096
// grid = 16 (z = d*8+b), block = 256.
// ---------------------------------------------------------------------------
__global__ __launch_bounds__(256)
void stats_k(const float* __restrict__ E, const float* __restrict__ GE,
             const float* __restrict__ GW, const float* __restrict__ WkT,
             float* __restrict__ rOut)
{
    const int z = blockIdx.x;
    const int tid = threadIdx.x;
    const int cp = tid & 63, q = tid >> 6;
    __shared__ float wp[4][64];
    float wk = 0.f;
    for (int ch = q; ch < 512; ch += 4) wk += WkT[ch * 64 + cp];
    wp[q][cp] = wk;
    __syncthreads();
    const float wkF = wp[0][cp] + wp[1][cp] + wp[2][cp] + wp[3][cp];

    float s1 = 0.f, s2 = 0.f;
    for (int bp = 0; bp < 8; bp++) {
        const float* Eb = E + (long long)(z * 8 + bp) * 32768;
        float es = 0.f;
        for (int i = q; i < 512; i += 4) es += Eb[i * 64 + cp];
        s1 += es;
        const float* Gb = GE + (long long)(z * 8 + bp) * 4096;
        for (int t = tid; t < 4096; t += 256) s2 += Gb[t] * GW[t];
    }
    s1 *= wkF;

    const int lane = tid & 63, w = tid >> 6;
#pragma unroll
    for (int off = 32; off; off >>= 1) {
        s1 += __shfl_down(s1, off, 64);
        s2 += __shfl_down(s2, off, 64);
    }
    __shared__ float r1[4], r2[4];
    if (lane == 0) { r1[w] = s1; r2[w] = s2; }
    __syncthreads();
    if (tid == 0) {
        float S1 = r1[0] + r1[1] + r1[2] + r1[3];
        float S2 = r2[0] + r2[1] + r2[2] + r2[3];
        const float inv = 1.f / 2097152.f;
        float mu = S1 * inv;
        float var = S2 * inv - mu * mu;
        rOut[z] = rsqrtf(var + EPS);
    }
}

// ---------------------------------------------------------------------------
// Pipeline (both directions batched in every dispatch; z = d*8+b or pairs):
//   G[d,b,b']   = Xq_b^T Xkv_b'      64x64, K=2048, split-K4 atomics
//   E_T[pair]   = [c'][i] = Wq^T G   64x512
//   E[pair]     = [i][c'] = (Wq^T G)^T  512x64
//   GW = WkT^T WkT, GE[pair] = E^T E  -> stats_k -> r[16]  (analytic IN)
//   expS[d,b]   = exp(r * (E_T^T Wk))  512x4096, fused rowsum atomics -> rs
//   U2[d,b]     = expS^T (Wo / rs)     4096x64   (softmax norm folded in)
//   Z[d,b,b']   = WvT^T U2-block       64x64
//   out[d,b]    = XT2_kv^T Zstack      2048x64
//
// Workspace (floats, ~162 MB peak with aliasing):
//   XT2  @ 0         2097152    (emb transposed, 16 x [64x2048])
//   WkT  @ 2097152   32768
//   WvT  @ 2129920   32768
//   G    @ 2162688   524288     [memset with rs]
//   rs   @ 2686976   8192       [memset]
//   r    @ 2695168   16
//   E_T  @ 2695184   4194304    -> U2 aliases after expS-gemm consumes E_T
//   E    @ 6889488   4194304    -> expS (33554432) aliases from here
//   GW   @ 11083792  4096       (inside expS region, dead before it)
//   GE   @ 11087888  524288     (inside expS region, dead before it)
//   expS @ 6889488   33554432
//   U2   @ 2695184   4194304    (alias E_T)
//   Zst  @ 6889488   524288     (alias expS head, after U2-gemm reads expS)
// ---------------------------------------------------------------------------
extern "C" void kernel_launch(void* const* d_in, const int* in_sizes, int n_in,
                              void* d_out, int out_size, void* d_ws, size_t ws_size,
                              hipStream_t stream)
{
    const float* emb = (const float*)d_in[0];
    const float* Wq  = (const float*)d_in[1];
    const float* Wk  = (const float*)d_in[2];
    const float* Wv  = (const float*)d_in[3];
    const float* Wo  = (const float*)d_in[4];
    float* out = (float*)d_out;
    float* ws  = (float*)d_ws;

    float* XT2  = ws;
    float* WkT  = ws + 2097152;
    float* WvT  = ws + 2129920;
    float* G    = ws + 2162688;
    float* rs   = ws + 2686976;
    float* r    = ws + 2695168;
    float* E_T  = ws + 2695184;
    float* E    = ws + 6889488;
    float* GW   = ws + 11083792;
    float* GE   = ws + 11087888;
    float* expS = ws + 6889488;
    float* U2   = ws + 2695184;
    float* Zst  = ws + 6889488;

    transpose_k<<<dim3(1, 32, 16), 256, 0, stream>>>(emb, XT2, 2048, 64, 64, 2048, 131072LL, 131072LL);
    transpose_k<<<dim3(8, 1, 1), 256, 0, stream>>>(Wk, WkT, 64, 512, 512, 64, 0, 0);
    transpose_k<<<dim3(8, 1, 1), 256, 0, stream>>>(Wv, WvT, 64, 512, 512, 64, 0, 0);
    hipMemsetAsync(G, 0, 532496 * sizeof(float), stream);  // G + rs + r

    // G[z=d*64+b*8+b'] = emb[d*8+b]^T @ emb_kv[b']   (kv half = opposite of q)
    gemm_tn<64, 64, 16, 4, 4, 4, false, false><<<dim3(1, 4, 128), 256, 0, stream>>>(
        emb, emb + 1048576, G, 2048, 64, 64, 64,
        8, 131072LL, 1, 0LL,
        64, -1048576LL, 8, 131072LL,
        1, 4096LL, 1, 0LL,
        nullptr, 1, nullptr, nullptr, 0);

    // E_T[pair][c'][i] = sum_c G[c][c'] * Wq[c][i]
    gemm_tn<64, 64, 16, 4, 4, 1, false, false><<<dim3(8, 1, 128), 256, 0, stream>>>(
        G, Wq, E_T, 64, 64, 512, 512,
        1, 4096LL, 1, 0LL,  1, 0LL, 1, 0LL,  1, 32768LL, 1, 0LL,
        nullptr, 1, nullptr, nullptr, 0);

    // E[pair][i][c'] = sum_c Wq[c][i] * G[c][c']
    gemm_tn<64, 64, 16, 4, 4, 1, false, false><<<dim3(1, 8, 128), 256, 0, stream>>>(
        Wq, G, E, 64, 512, 64, 64,
        1, 0LL, 1, 0LL,  1, 4096LL, 1, 0LL,  1, 32768LL, 1, 0LL,
        nullptr, 1, nullptr, nullptr, 0);

    // GW = WkT^T @ WkT (64x64, K=512)
    gemm_tn<64, 64, 16, 2, 2, 1, false, false><<<dim3(1, 1, 1), 1024, 0, stream>>>(
        WkT, WkT, GW, 512, 64, 64, 64,
        1, 0LL, 1, 0LL,  1, 0LL, 1, 0LL,  1, 0LL, 1, 0LL,
        nullptr, 1, nullptr, nullptr, 0);

    // GE[pair] = E^T @ E (64x64, K=512)
    gemm_tn<64, 64, 16, 4, 4, 1, false, false><<<dim3(1, 1, 128), 256, 0, stream>>>(
        E, E, GE, 512, 64, 64, 64,
        1, 32768LL, 1, 0LL,  1, 32768LL, 1, 0LL,  1, 4096LL, 1, 0LL,
        nullptr, 1, nullptr, nullptr, 0);

    stats_k<<<16, 256, 0, stream>>>(E, GE, GW, WkT, r);

    // expS[d,b][i][b'*512+ch] = exp(r * sum_c' E_T[c'][i]*Wk[c'][ch]); rowsum->rs
    gemm_tn<128, 128, 16, 8, 8, 1, true, false><<<dim3(4, 4, 128), 256, 0, stream>>>(
        E_T, Wk, expS, 64, 512, 512, 4096,
        1, 32768LL, 1, 0LL,
        1, 0LL, 1, 0LL,
        8, 2097152LL, 8, 512LL,
        r, 8, rs, nullptr, 0);

    // U2[d,b][j][o] = sum_i expS[i][j] * Wo[i][o]/rs[i]
    gemm_tn<64, 64, 16, 4, 4, 1, false, true><<<dim3(1, 64, 16), 256, 0, stream>>>(
        expS, Wo, U2, 512, 4096, 64, 64,
        1, 2097152LL, 1, 0LL,
        1, 0LL, 1, 0LL,
        1, 262144LL, 1, 0LL,
        nullptr, 1, nullptr, rs, 512);

    // Z[d,b,b'][c][o] = sum_ch WvT[ch][c] * U2[b'*512+ch][o]
    gemm_tn<64, 64, 16, 4, 4, 1, false, false><<<dim3(1, 1, 128), 256, 0, stream>>>(
        WvT, U2, Zst, 512, 64, 64, 64,
        1, 0LL, 1, 0LL,
        8, 262144LL, 8, 32768LL,
        1, 4096LL, 1, 0LL,
        nullptr, 1, nullptr, nullptr, 0);

    // out[d*8+b][n][c] = sum_{b'c} XT2_kv[b'*64+c][n] * Zst[b'*64+c][o]
    gemm_tn<64, 64, 16, 4, 4, 1, false, false><<<dim3(1, 32, 16), 256, 0, stream>>>(
        XT2 + 1048576, Zst, out, 512, 2048, 64, 64,
        8, -1048576LL, 1, 0LL,
        1, 32768LL, 1, 0LL,
        1, 131072LL, 1, 0LL,
        nullptr, 1, nullptr, nullptr, 0);
}

// Round 4
// 469.325 us; speedup vs baseline: 8.0784x; 1.6496x over previous
//
#include <hip/hip_runtime.h>

#define EPS 1e-5f

// ---------------------------------------------------------------------------
// Generalized batched TN GEMM: C[m][n] = sum_k A[k][m] * B[k][n]
// Offsets per z = blockIdx.z:  off = (z/div)*bsd + (z%mod)*bsm
// KS>1: split-K, atomicAdd into pre-zeroed C. grid.y = Mtiles*KS.
// EXPSM: epilogue writes exp(r*acc) and atomicAdds per-row sums into
//        rsPtr[(z/rDiv)*512 + row] (rs pre-zeroed). Requires BN/TN==16.
// BSCALE: B rows scaled by 1/sPtr[z*sStride + k] at LDS staging.
// ---------------------------------------------------------------------------
template<int BM, int BN, int BK, int TM, int TN, int KS, bool EXPSM, bool BSCALE>
__global__ __launch_bounds__((BM/TM)*(BN/TN))
void gemm_tn(const float* __restrict__ A, const float* __restrict__ B,
             float* __restrict__ C, int K,
             int lda, int ldb, int ldc,
             int divA, long long bsAd, int modA, long long bsAm,
             int divB, long long bsBd, int modB, long long bsBm,
             int divC, long long bsCd, int modC, long long bsCm,
             const float* __restrict__ rPtr, int rDiv, float* __restrict__ rsPtr,
             const float* __restrict__ sPtr, int sStride)
{
    constexpr int T  = (BM/TM)*(BN/TN);
    constexpr int HM = TM/2, HN = TN/2;
    __shared__ float As[BK][BM];
    __shared__ float Bs[BK][BN];

    const int tid = threadIdx.x;
    const int z = blockIdx.z;
    const int mtile = blockIdx.y / KS;
    const int ks = blockIdx.y % KS;
    const int n0 = blockIdx.x * BN;
    const int m0 = mtile * BM;
    A += (long long)(z / divA) * bsAd + (long long)(z % modA) * bsAm;
    B += (long long)(z / divB) * bsBd + (long long)(z % modB) * bsBm;
    C += (long long)(z / divC) * bsCd + (long long)(z % modC) * bsCm;

    const int tx = tid % (BN/TN);
    const int ty = tid / (BN/TN);

    float acc[TM][TN] = {};

    const int kc = K / KS;
    const int kBeg = ks * kc;
    const long long sOff = BSCALE ? (long long)z * sStride : 0;

    for (int k0 = kBeg; k0 < kBeg + kc; k0 += BK) {
#pragma unroll
        for (int idx = tid * 4; idx < BK * BM; idx += T * 4) {
            int rr = idx / BM, cc = idx % BM;
            *(float4*)&As[rr][cc] = *(const float4*)(A + (long long)(k0 + rr) * lda + m0 + cc);
        }
#pragma unroll
        for (int idx = tid * 4; idx < BK * BN; idx += T * 4) {
            int rr = idx / BN, cc = idx % BN;
            float4 bv = *(const float4*)(B + (long long)(k0 + rr) * ldb + n0 + cc);
            if (BSCALE) {
                float inv = 1.0f / sPtr[sOff + k0 + rr];
                bv.x *= inv; bv.y *= inv; bv.z *= inv; bv.w *= inv;
            }
            *(float4*)&Bs[rr][cc] = bv;
        }
        __syncthreads();
#pragma unroll
        for (int kk = 0; kk < BK; kk++) {
            float a[TM], b[TN];
#pragma unroll
            for (int u = 0; u < HM; u++) {
                a[u]      = As[kk][ty * HM + u];
                a[HM + u] = As[kk][BM / 2 + ty * HM + u];
            }
#pragma unroll
            for (int v = 0; v < HN; v++) {
                b[v]      = Bs[kk][tx * HN + v];
                b[HN + v] = Bs[kk][BN / 2 + tx * HN + v];
            }
#pragma unroll
            for (int u = 0; u < TM; u++)
#pragma unroll
                for (int v = 0; v < TN; v++)
                    acc[u][v] += a[u] * b[v];
        }
        __syncthreads();
    }

    if (EXPSM) {
        const float rv = rPtr[z / rDiv];
        const long long rsBase = (long long)(z / rDiv) * 512 + m0;
#pragma unroll
        for (int u = 0; u < TM; u++) {
            int rl = (u < HM) ? ty * HM + u : BM / 2 + ty * HM + (u - HM);
            float ev[TN];
            float p = 0.f;
#pragma unroll
            for (int v = 0; v < TN; v++) { ev[v] = __expf(rv * acc[u][v]); p += ev[v]; }
            float* cr = C + (long long)(m0 + rl) * ldc + n0;
            if (HN == 4) {
                *(float4*)(cr + tx * HN) = make_float4(ev[0], ev[1], ev[2], ev[3]);
                *(float4*)(cr + BN / 2 + tx * HN) = make_float4(ev[4], ev[5], ev[6], ev[7]);
            }
#pragma unroll
            for (int off = 8; off; off >>= 1) p += __shfl_down(p, off, 16);
            if (tx == 0) atomicAdd(&rsPtr[rsBase + rl], p);
        }
    } else if (KS > 1) {
#pragma unroll
        for (int u = 0; u < TM; u++) {
            int rl = (u < HM) ? ty * HM + u : BM / 2 + ty * HM + (u - HM);
#pragma unroll
            for (int v = 0; v < TN; v++) {
                int cl = (v < HN) ? tx * HN + v : BN / 2 + tx * HN + (v - HN);
                atomicAdd(&C[(long long)(m0 + rl) * ldc + n0 + cl], acc[u][v]);
            }
        }
    } else {
#pragma unroll
        for (int u = 0; u < TM; u++) {
            int rl = (u < HM) ? ty * HM + u : BM / 2 + ty * HM + (u - HM);
            float* cr = C + (long long)(m0 + rl) * ldc + n0;
            if (HN == 4) {
                *(float4*)(cr + tx * HN) = make_float4(acc[u][0], acc[u][1], acc[u][2], acc[u][3]);
                *(float4*)(cr + BN / 2 + tx * HN) = make_float4(acc[u][4], acc[u][5], acc[u][6], acc[u][7]);
            } else if (HN == 2) {
                *(float2*)(cr + tx * HN) = make_float2(acc[u][0], acc[u][1]);
                *(float2*)(cr + BN / 2 + tx * HN) = make_float2(acc[u][2], acc[u][3]);
            } else {
#pragma unroll
                for (int v = 0; v < HN; v++) {
                    cr[tx * HN + v] = acc[u][v];
                    cr[BN / 2 + tx * HN + v] = acc[u][HN + v];
                }
            }
        }
    }
}

// ---------------------------------------------------------------------------
// 64x64 LDS tile transpose
// ---------------------------------------------------------------------------
__global__ __launch_bounds__(256)
void transpose_k(const float* __restrict__ in, float* __restrict__ out,
                 int rows, int cols, int ldin, int ldout,
                 long long bsIn, long long bsOut)
{
    __shared__ float t[64][65];
    in += blockIdx.z * bsIn;
    out += blockIdx.z * bsOut;
    const int c0 = blockIdx.x * 64, r0 = blockIdx.y * 64;
    const int c = threadIdx.x & 63, r4 = threadIdx.x >> 6;
#pragma unroll
    for (int rr = r4; rr < 64; rr += 4)
        t[rr][c] = in[(long long)(r0 + rr) * ldin + c0 + c];
    __syncthreads();
#pragma unroll
    for (int rr = r4; rr < 64; rr += 4)
        out[(long long)(c0 + rr) * ldout + r0 + c] = t[c][rr];
}

// ---------------------------------------------------------------------------
// Row sums of the 64x512 weight matrices: wqs[c] = sum_i Wq[c][i], same Wk.
// grid 2 (0 -> Wq, 1 -> Wk), block 256.
// ---------------------------------------------------------------------------
__global__ __launch_bounds__(256)
void wsum_k(const float* __restrict__ Wq, const float* __restrict__ Wk,
            float* __restrict__ wqs, float* __restrict__ wks)
{
    const float* W = blockIdx.x ? Wk : Wq;
    float* o = blockIdx.x ? wks : wqs;
    __shared__ float acc[64];
    if (threadIdx.x < 64) acc[threadIdx.x] = 0.f;
    __syncthreads();
    for (int idx = threadIdx.x * 4; idx < 32768; idx += 1024) {
        float4 v = *(const float4*)(W + idx);
        atomicAdd(&acc[idx >> 9], v.x + v.y + v.z + v.w);
    }
    __syncthreads();
    if (threadIdx.x < 64) o[threadIdx.x] = acc[threadIdx.x];
}

// ---------------------------------------------------------------------------
// Analytic InstanceNorm stats from 64x64 Grams (E is never materialized):
//   s1_pair = wqs^T G_pair wks
//   s2_pair = <GQ*G_pair, G_pair*GW>   (= tr(G^T GQ G GW) = ||S_pair||_F^2)
// atomicAdd into sums[(pair/8)*2 + {0,1}]. grid 128 pairs, block 256.
// ---------------------------------------------------------------------------
__global__ __launch_bounds__(256)
void stats2_k(const float* __restrict__ G, const float* __restrict__ GQ,
              const float* __restrict__ GW, const float* __restrict__ wqs,
              const float* __restrict__ wks, float* __restrict__ sums)
{
    __shared__ float Gs[64][68], GQs[64][68], GWs[64][68];
    const int tid = threadIdx.x;
    const float* Gp = G + (long long)blockIdx.x * 4096;
    for (int f = tid * 4; f < 4096; f += 1024) {
        int rr = f >> 6, cc = f & 63;
        *(float4*)&Gs[rr][cc]  = *(const float4*)(Gp + f);
        *(float4*)&GQs[rr][cc] = *(const float4*)(GQ + f);
        *(float4*)&GWs[rr][cc] = *(const float4*)(GW + f);
    }
    __syncthreads();
    const int r = tid >> 2;
    const int c0 = (tid & 3) * 16;
    float p1[16] = {}, p2[16] = {};
    for (int k = 0; k < 64; k++) {
        float gq = GQs[r][k], g = Gs[r][k];
#pragma unroll
        for (int j = 0; j < 16; j++) {
            p1[j] += gq * Gs[k][c0 + j];
            p2[j] += g  * GWs[k][c0 + j];
        }
    }
    float s2 = 0.f;
#pragma unroll
    for (int j = 0; j < 16; j++) s2 += p1[j] * p2[j];
    float s1 = 0.f;
    const float wq = wqs[r];
#pragma unroll
    for (int j = 0; j < 16; j++) s1 += wq * Gs[r][c0 + j] * wks[c0 + j];

    const int lane = tid & 63, w = tid >> 6;
#pragma unroll
    for (int off = 32; off; off >>= 1) {
        s1 += __shfl_down(s1, off, 64);
        s2 += __shfl_down(s2, off, 64);
    }
    __shared__ float r1[4], r2[4];
    if (lane == 0) { r1[w] = s1; r2[w] = s2; }
    __syncthreads();
    if (tid == 0) {
        atomicAdd(&sums[(blockIdx.x >> 3) * 2],     r1[0] + r1[1] + r1[2] + r1[3]);
        atomicAdd(&sums[(blockIdx.x >> 3) * 2 + 1], r2[0] + r2[1] + r2[2] + r2[3]);
    }
}

__global__ void fin_k(const float* __restrict__ sums, float* __restrict__ r)
{
    const int t = threadIdx.x;  // 16
    const float inv = 1.f / 2097152.f;
    float mu  = sums[2 * t] * inv;
    float var = sums[2 * t + 1] * inv - mu * mu;
    r[t] = rsqrtf(var + EPS);
}

// ---------------------------------------------------------------------------
// Pipeline:
//   G[d,b,b'] = Xq_b^T Xkv_b'        64x64, K=2048, split-K4 atomics
//   GQ = Wq Wq^T, GW = Wk Wk^T, wqs/wks row sums
//   stats2 + fin -> r[16]            (analytic InstanceNorm; E never stored)
//   E_T[pair]  = Wq^T G              64x512
//   expS[d,b]  = exp(r*(E_T^T Wk))   512x4096, fused rowsum atomics -> rs
//   U2[d,b]    = expS^T (Wo / rs)    4096x64
//   Z[d,b,b']  = WvT^T U2-block      64x64
//   out[d,b]   = XT2_kv^T Zstack     2048x64
//
// Workspace (floats):
//   XT2 @0:2097152 | WkT @2097152 | WvT @2129920 | WqT @2162688
//   G @2195456:524288 | rs @2719744:8192 | sums @2727936:32 | r @2727968:16
//   wqs @2727984:64 | wks @2728048:64 | GQ @2728112:4096 | GW @2732208:4096
//   E_T @2736304:4194304 (U2 aliases after expS consumes it)
//   expS @6930608:33554432 (Zst aliases head after U2 reads it)
// ---------------------------------------------------------------------------
extern "C" void kernel_launch(void* const* d_in, const int* in_sizes, int n_in,
                              void* d_out, int out_size, void* d_ws, size_t ws_size,
                              hipStream_t stream)
{
    const float* emb = (const float*)d_in[0];
    const float* Wq  = (const float*)d_in[1];
    const float* Wk  = (const float*)d_in[2];
    const float* Wv  = (const float*)d_in[3];
    const float* Wo  = (const float*)d_in[4];
    float* out = (float*)d_out;
    float* ws  = (float*)d_ws;

    float* XT2  = ws;
    float* WkT  = ws + 2097152;
    float* WvT  = ws + 2129920;
    float* WqT  = ws + 2162688;
    float* G    = ws + 2195456;
    float* rs   = ws + 2719744;
    float* sums = ws + 2727936;
    float* r    = ws + 2727968;
    float* wqs  = ws + 2727984;
    float* wks  = ws + 2728048;
    float* GQ   = ws + 2728112;
    float* GW   = ws + 2732208;
    float* E_T  = ws + 2736304;
    float* expS = ws + 6930608;
    float* U2   = E_T;   // alias (E_T dead after expS gemm)
    float* Zst  = expS;  // alias (expS head dead after U2 gemm)

    transpose_k<<<dim3(1, 32, 16), 256, 0, stream>>>(emb, XT2, 2048, 64, 64, 2048, 131072LL, 131072LL);
    transpose_k<<<dim3(8, 1, 1), 256, 0, stream>>>(Wq, WqT, 64, 512, 512, 64, 0, 0);
    transpose_k<<<dim3(8, 1, 1), 256, 0, stream>>>(Wk, WkT, 64, 512, 512, 64, 0, 0);
    transpose_k<<<dim3(8, 1, 1), 256, 0, stream>>>(Wv, WvT, 64, 512, 512, 64, 0, 0);
    hipMemsetAsync(G, 0, 532512 * sizeof(float), stream);  // G + rs + sums
    wsum_k<<<2, 256, 0, stream>>>(Wq, Wk, wqs, wks);

    // G[z=d*64+b*8+b'] = emb_q[d,b]^T @ emb_kv[d,b']   K=2048 split-K4
    gemm_tn<64, 64, 16, 4, 4, 4, false, false><<<dim3(1, 4, 128), 256, 0, stream>>>(
        emb, emb + 1048576, G, 2048, 64, 64, 64,
        8, 131072LL, 1, 0LL,
        64, -1048576LL, 8, 131072LL,
        1, 4096LL, 1, 0LL,
        nullptr, 1, nullptr, nullptr, 0);

    // GQ = WqT^T WqT, GW = WkT^T WkT   (64x64, K=512)
    gemm_tn<64, 64, 16, 4, 4, 1, false, false><<<dim3(1, 1, 1), 256, 0, stream>>>(
        WqT, WqT, GQ, 512, 64, 64, 64,
        1, 0LL, 1, 0LL,  1, 0LL, 1, 0LL,  1, 0LL, 1, 0LL,
        nullptr, 1, nullptr, nullptr, 0);
    gemm_tn<64, 64, 16, 4, 4, 1, false, false><<<dim3(1, 1, 1), 256, 0, stream>>>(
        WkT, WkT, GW, 512, 64, 64, 64,
        1, 0LL, 1, 0LL,  1, 0LL, 1, 0LL,  1, 0LL, 1, 0LL,
        nullptr, 1, nullptr, nullptr, 0);

    stats2_k<<<128, 256, 0, stream>>>(G, GQ, GW, wqs, wks, sums);
    fin_k<<<1, 16, 0, stream>>>(sums, r);

    // E_T[pair][c'][i] = sum_c G[c][c'] * Wq[c][i]
    gemm_tn<64, 64, 16, 4, 4, 1, false, false><<<dim3(8, 1, 128), 256, 0, stream>>>(
        G, Wq, E_T, 64, 64, 512, 512,
        1, 4096LL, 1, 0LL,  1, 0LL, 1, 0LL,  1, 32768LL, 1, 0LL,
        nullptr, 1, nullptr, nullptr, 0);

    // expS[d,b][i][b'*512+ch] = exp(r * sum_c' E_T[c'][i]*Wk[c'][ch]); rowsum->rs
    gemm_tn<128, 128, 16, 8, 8, 1, true, false><<<dim3(4, 4, 128), 256, 0, stream>>>(
        E_T, Wk, expS, 64, 512, 512, 4096,
        1, 32768LL, 1, 0LL,
        1, 0LL, 1, 0LL,
        8, 2097152LL, 8, 512LL,
        r, 8, rs, nullptr, 0);

    // U2[d,b][j][o] = sum_i expS[i][j] * Wo[i][o]/rs[i]
    gemm_tn<64, 64, 16, 4, 4, 1, false, true><<<dim3(1, 64, 16), 256, 0, stream>>>(
        expS, Wo, U2, 512, 4096, 64, 64,
        1, 2097152LL, 1, 0LL,
        1, 0LL, 1, 0LL,
        1, 262144LL, 1, 0LL,
        nullptr, 1, nullptr, rs, 512);

    // Z[d,b,b'][c][o] = sum_ch WvT[ch][c] * U2[b'*512+ch][o]
    gemm_tn<64, 64, 16, 4, 4, 1, false, false><<<dim3(1, 1, 128), 256, 0, stream>>>(
        WvT, U2, Zst, 512, 64, 64, 64,
        1, 0LL, 1, 0LL,
        8, 262144LL, 8, 32768LL,
        1, 4096LL, 1, 0LL,
        nullptr, 1, nullptr, nullptr, 0);

    // out[d*8+b][n][c] = sum_{b',c} XT2_kv[b'*64+c][n] * Zst[b'*64+c][o]
    gemm_tn<64, 64, 16, 4, 4, 1, false, false><<<dim3(1, 32, 16), 256, 0, stream>>>(
        XT2 + 1048576, Zst, out, 512, 2048, 64, 64,
        8, -1048576LL, 1, 0LL,
        1, 32768LL, 1, 0LL,
        1, 131072LL, 1, 0LL,
        nullptr, 1, nullptr, nullptr, 0);
}

// Round 5
// 458.912 us; speedup vs baseline: 8.2617x; 1.0227x over previous
//
#include <hip/hip_runtime.h>
#include <hip/hip_fp16.h>

#define EPS 1e-5f

// ---------------------------------------------------------------------------
// Generalized batched TN GEMM: C[m][n] = sum_k A[k][m] * B[k][n]
// Offsets per z = blockIdx.z:  off = (z/div)*bsd + (z%mod)*bsm  (element units)
// KS>1: split-K, atomicAdd into pre-zeroed C. grid.y = Mtiles*KS.
// EXPSM: epilogue writes exp(r*acc) (as TC, fp16 supported) and atomicAdds
//        per-row fp32 sums into rsPtr[(z/rDiv)*512 + row]. Requires BN/TN==16.
// BSCALE: B rows scaled by 1/sPtr[z*sStride + k] at LDS staging.
// TA: A element type (float or __half; converted to fp32 at LDS staging).
// ---------------------------------------------------------------------------
template<int BM, int BN, int BK, int TM, int TN, int KS, bool EXPSM, bool BSCALE,
         typename TA, typename TC>
__global__ __launch_bounds__((BM/TM)*(BN/TN))
void gemm_tn(const TA* __restrict__ A, const float* __restrict__ B,
             TC* __restrict__ C, int K,
             int lda, int ldb, int ldc,
             int divA, long long bsAd, int modA, long long bsAm,
             int divB, long long bsBd, int modB, long long bsBm,
             int divC, long long bsCd, int modC, long long bsCm,
             const float* __restrict__ rPtr, int rDiv, float* __restrict__ rsPtr,
             const float* __restrict__ sPtr, int sStride)
{
    constexpr int T  = (BM/TM)*(BN/TN);
    constexpr int HM = TM/2, HN = TN/2;
    __shared__ float As[BK][BM];
    __shared__ float Bs[BK][BN];

    const int tid = threadIdx.x;
    const int z = blockIdx.z;
    const int mtile = blockIdx.y / KS;
    const int ks = blockIdx.y % KS;
    const int n0 = blockIdx.x * BN;
    const int m0 = mtile * BM;
    A += (long long)(z / divA) * bsAd + (long long)(z % modA) * bsAm;
    B += (long long)(z / divB) * bsBd + (long long)(z % modB) * bsBm;
    C += (long long)(z / divC) * bsCd + (long long)(z % modC) * bsCm;

    const int tx = tid % (BN/TN);
    const int ty = tid / (BN/TN);

    float acc[TM][TN] = {};

    const int kc = K / KS;
    const int kBeg = ks * kc;
    const long long sOff = BSCALE ? (long long)z * sStride : 0;

    for (int k0 = kBeg; k0 < kBeg + kc; k0 += BK) {
#pragma unroll
        for (int idx = tid * 4; idx < BK * BM; idx += T * 4) {
            int rr = idx / BM, cc = idx % BM;
            if constexpr (sizeof(TA) == 2) {
                const __half* Ah = (const __half*)(A + (long long)(k0 + rr) * lda + m0 + cc);
                float2 f0 = __half22float2(*(const __half2*)Ah);
                float2 f1 = __half22float2(*(const __half2*)(Ah + 2));
                As[rr][cc] = f0.x; As[rr][cc + 1] = f0.y;
                As[rr][cc + 2] = f1.x; As[rr][cc + 3] = f1.y;
            } else {
                *(float4*)&As[rr][cc] = *(const float4*)(A + (long long)(k0 + rr) * lda + m0 + cc);
            }
        }
#pragma unroll
        for (int idx = tid * 4; idx < BK * BN; idx += T * 4) {
            int rr = idx / BN, cc = idx % BN;
            float4 bv = *(const float4*)(B + (long long)(k0 + rr) * ldb + n0 + cc);
            if (BSCALE) {
                float inv = 1.0f / sPtr[sOff + k0 + rr];
                bv.x *= inv; bv.y *= inv; bv.z *= inv; bv.w *= inv;
            }
            *(float4*)&Bs[rr][cc] = bv;
        }
        __syncthreads();
#pragma unroll
        for (int kk = 0; kk < BK; kk++) {
            float a[TM], b[TN];
#pragma unroll
            for (int u = 0; u < HM; u++) {
                a[u]      = As[kk][ty * HM + u];
                a[HM + u] = As[kk][BM / 2 + ty * HM + u];
            }
#pragma unroll
            for (int v = 0; v < HN; v++) {
                b[v]      = Bs[kk][tx * HN + v];
                b[HN + v] = Bs[kk][BN / 2 + tx * HN + v];
            }
#pragma unroll
            for (int u = 0; u < TM; u++)
#pragma unroll
                for (int v = 0; v < TN; v++)
                    acc[u][v] += a[u] * b[v];
        }
        __syncthreads();
    }

    if constexpr (EXPSM) {
        const float rv = rPtr[z / rDiv];
        const long long rsBase = (long long)(z / rDiv) * 512 + m0;
#pragma unroll
        for (int u = 0; u < TM; u++) {
            int rl = (u < HM) ? ty * HM + u : BM / 2 + ty * HM + (u - HM);
            float ev[TN];
            float p = 0.f;
#pragma unroll
            for (int v = 0; v < TN; v++) { ev[v] = __expf(rv * acc[u][v]); p += ev[v]; }
            TC* cr = C + (long long)(m0 + rl) * ldc + n0;
            if constexpr (sizeof(TC) == 2) {
                __half2* c0 = (__half2*)(cr + tx * HN);
                c0[0] = __floats2half2_rn(ev[0], ev[1]);
                c0[1] = __floats2half2_rn(ev[2], ev[3]);
                __half2* c1 = (__half2*)(cr + BN / 2 + tx * HN);
                c1[0] = __floats2half2_rn(ev[4], ev[5]);
                c1[1] = __floats2half2_rn(ev[6], ev[7]);
            } else {
                *(float4*)(cr + tx * HN) = make_float4(ev[0], ev[1], ev[2], ev[3]);
                *(float4*)(cr + BN / 2 + tx * HN) = make_float4(ev[4], ev[5], ev[6], ev[7]);
            }
#pragma unroll
            for (int off = 8; off; off >>= 1) p += __shfl_down(p, off, 16);
            if (tx == 0) atomicAdd(&rsPtr[rsBase + rl], p);
        }
    } else if constexpr (KS > 1) {
#pragma unroll
        for (int u = 0; u < TM; u++) {
            int rl = (u < HM) ? ty * HM + u : BM / 2 + ty * HM + (u - HM);
#pragma unroll
            for (int v = 0; v < TN; v++) {
                int cl = (v < HN) ? tx * HN + v : BN / 2 + tx * HN + (v - HN);
                atomicAdd(&C[(long long)(m0 + rl) * ldc + n0 + cl], acc[u][v]);
            }
        }
    } else {
#pragma unroll
        for (int u = 0; u < TM; u++) {
            int rl = (u < HM) ? ty * HM + u : BM / 2 + ty * HM + (u - HM);
            TC* cr = C + (long long)(m0 + rl) * ldc + n0;
            if constexpr (HN == 4) {
                *(float4*)(cr + tx * HN) = make_float4(acc[u][0], acc[u][1], acc[u][2], acc[u][3]);
                *(float4*)(cr + BN / 2 + tx * HN) = make_float4(acc[u][4], acc[u][5], acc[u][6], acc[u][7]);
            } else if constexpr (HN == 2) {
                *(float2*)(cr + tx * HN) = make_float2(acc[u][0], acc[u][1]);
                *(float2*)(cr + BN / 2 + tx * HN) = make_float2(acc[u][2], acc[u][3]);
            } else {
#pragma unroll
                for (int v = 0; v < HN; v++) {
                    cr[tx * HN + v] = acc[u][v];
                    cr[BN / 2 + tx * HN + v] = acc[u][HN + v];
                }
            }
        }
    }
}

// ---------------------------------------------------------------------------
// 64x64 LDS tile transpose
// ---------------------------------------------------------------------------
__global__ __launch_bounds__(256)
void transpose_k(const float* __restrict__ in, float* __restrict__ out,
                 int rows, int cols, int ldin, int ldout,
                 long long bsIn, long long bsOut)
{
    __shared__ float t[64][65];
    in += blockIdx.z * bsIn;
    out += blockIdx.z * bsOut;
    const int c0 = blockIdx.x * 64, r0 = blockIdx.y * 64;
    const int c = threadIdx.x & 63, r4 = threadIdx.x >> 6;
#pragma unroll
    for (int rr = r4; rr < 64; rr += 4)
        t[rr][c] = in[(long long)(r0 + rr) * ldin + c0 + c];
    __syncthreads();
#pragma unroll
    for (int rr = r4; rr < 64; rr += 4)
        out[(long long)(c0 + rr) * ldout + r0 + c] = t[c][rr];
}

// ---------------------------------------------------------------------------
// Row sums of the 64x512 weight matrices: wqs[c] = sum_i Wq[c][i], same Wk.
// ---------------------------------------------------------------------------
__global__ __launch_bounds__(256)
void wsum_k(const float* __restrict__ Wq, const float* __restrict__ Wk,
            float* __restrict__ wqs, float* __restrict__ wks)
{
    const float* W = blockIdx.x ? Wk : Wq;
    float* o = blockIdx.x ? wks : wqs;
    __shared__ float acc[64];
    if (threadIdx.x < 64) acc[threadIdx.x] = 0.f;
    __syncthreads();
    for (int idx = threadIdx.x * 4; idx < 32768; idx += 1024) {
        float4 v = *(const float4*)(W + idx);
        atomicAdd(&acc[idx >> 9], v.x + v.y + v.z + v.w);
    }
    __syncthreads();
    if (threadIdx.x < 64) o[threadIdx.x] = acc[threadIdx.x];
}

// ---------------------------------------------------------------------------
// Analytic InstanceNorm stats from 64x64 Grams (E never materialized):
//   s1_pair = wqs^T G_pair wks
//   s2_pair = <GQ*G_pair, G_pair*GW>   (= ||S_pair||_F^2)
// ---------------------------------------------------------------------------
__global__ __launch_bounds__(256)
void stats2_k(const float* __restrict__ G, const float* __restrict__ GQ,
              const float* __restrict__ GW, const float* __restrict__ wqs,
              const float* __restrict__ wks, float* __restrict__ sums)
{
    __shared__ float Gs[64][68], GQs[64][68], GWs[64][68];
    const int tid = threadIdx.x;
    const float* Gp = G + (long long)blockIdx.x * 4096;
    for (int f = tid * 4; f < 4096; f += 1024) {
        int rr = f >> 6, cc = f & 63;
        *(float4*)&Gs[rr][cc]  = *(const float4*)(Gp + f);
        *(float4*)&GQs[rr][cc] = *(const float4*)(GQ + f);
        *(float4*)&GWs[rr][cc] = *(const float4*)(GW + f);
    }
    __syncthreads();
    const int r = tid >> 2;
    const int c0 = (tid & 3) * 16;
    float p1[16] = {}, p2[16] = {};
    for (int k = 0; k < 64; k++) {
        float gq = GQs[r][k], g = Gs[r][k];
#pragma unroll
        for (int j = 0; j < 16; j++) {
            p1[j] += gq * Gs[k][c0 + j];
            p2[j] += g  * GWs[k][c0 + j];
        }
    }
    float s2 = 0.f;
#pragma unroll
    for (int j = 0; j < 16; j++) s2 += p1[j] * p2[j];
    float s1 = 0.f;
    const float wq = wqs[r];
#pragma unroll
    for (int j = 0; j < 16; j++) s1 += wq * Gs[r][c0 + j] * wks[c0 + j];

    const int lane = tid & 63, w = tid >> 6;
#pragma unroll
    for (int off = 32; off; off >>= 1) {
        s1 += __shfl_down(s1, off, 64);
        s2 += __shfl_down(s2, off, 64);
    }
    __shared__ float r1[4], r2[4];
    if (lane == 0) { r1[w] = s1; r2[w] = s2; }
    __syncthreads();
    if (tid == 0) {
        atomicAdd(&sums[(blockIdx.x >> 3) * 2],     r1[0] + r1[1] + r1[2] + r1[3]);
        atomicAdd(&sums[(blockIdx.x >> 3) * 2 + 1], r2[0] + r2[1] + r2[2] + r2[3]);
    }
}

__global__ void fin_k(const float* __restrict__ sums, float* __restrict__ r)
{
    const int t = threadIdx.x;  // 16
    const float inv = 1.f / 2097152.f;
    float mu  = sums[2 * t] * inv;
    float var = sums[2 * t + 1] * inv - mu * mu;
    r[t] = rsqrtf(var + EPS);
}

// ---------------------------------------------------------------------------
// Pipeline (expS now fp16; rs accumulated fp32 pre-conversion):
//   G[d,b,b'] = Xq_b^T Xkv_b'        64x64, K=2048, split-K4 atomics
//   GQ/GW Grams + wqs/wks + stats2 + fin -> r[16] (analytic InstanceNorm)
//   E_T[pair]  = Wq^T G              64x512
//   expS[d,b]  = exp(r*(E_T^T Wk))   512x4096 fp16, fused fp32 rowsums -> rs
//   U2[d,b]    = expS^T (Wo / rs)    4096x64  (fp16 A, BM=128/BK=32 tile)
//   Z[d,b,b']  = WvT^T U2-block      64x64
//   out[d,b]   = XT2_kv^T Zstack     2048x64
//
// Workspace (floats):
//   XT2 @0:2097152 | WkT @2097152 | WvT @2129920 | WqT @2162688
//   G @2195456:524288 | rs @2719744:8192 | sums @2727936:32 | r @2727968:16
//   wqs @2727984:64 | wks @2728048:64 | GQ @2728112:4096 | GW @2732208:4096
//   E_T @2736304:4194304 (U2 aliases after expS consumes it)
//   expS @6930608: 33554432 halves (=16777216 floats); Zst aliases head after U2
// ---------------------------------------------------------------------------
extern "C" void kernel_launch(void* const* d_in, const int* in_sizes, int n_in,
                              void* d_out, int out_size, void* d_ws, size_t ws_size,
                              hipStream_t stream)
{
    const float* emb = (const float*)d_in[0];
    const float* Wq  = (const float*)d_in[1];
    const float* Wk  = (const float*)d_in[2];
    const float* Wv  = (const float*)d_in[3];
    const float* Wo  = (const float*)d_in[4];
    float* out = (float*)d_out;
    float* ws  = (float*)d_ws;

    float* XT2  = ws;
    float* WkT  = ws + 2097152;
    float* WvT  = ws + 2129920;
    float* WqT  = ws + 2162688;
    float* G    = ws + 2195456;
    float* rs   = ws + 2719744;
    float* sums = ws + 2727936;
    float* r    = ws + 2727968;
    float* wqs  = ws + 2727984;
    float* wks  = ws + 2728048;
    float* GQ   = ws + 2728112;
    float* GW   = ws + 2732208;
    float* E_T  = ws + 2736304;
    __half* expS = (__half*)(ws + 6930608);
    float* U2   = E_T;            // alias (E_T dead after expS gemm)
    float* Zst  = ws + 6930608;   // alias expS head (dead after U2 gemm)

    transpose_k<<<dim3(1, 32, 16), 256, 0, stream>>>(emb, XT2, 2048, 64, 64, 2048, 131072LL, 131072LL);
    transpose_k<<<dim3(8, 1, 1), 256, 0, stream>>>(Wq, WqT, 64, 512, 512, 64, 0, 0);
    transpose_k<<<dim3(8, 1, 1), 256, 0, stream>>>(Wk, WkT, 64, 512, 512, 64, 0, 0);
    transpose_k<<<dim3(8, 1, 1), 256, 0, stream>>>(Wv, WvT, 64, 512, 512, 64, 0, 0);
    hipMemsetAsync(G, 0, 532512 * sizeof(float), stream);  // G + rs + sums
    wsum_k<<<2, 256, 0, stream>>>(Wq, Wk, wqs, wks);

    // G[z=d*64+b*8+b'] = emb_q[d,b]^T @ emb_kv[d,b']   K=2048 split-K4
    gemm_tn<64, 64, 16, 4, 4, 4, false, false, float, float><<<dim3(1, 4, 128), 256, 0, stream>>>(
        emb, emb + 1048576, G, 2048, 64, 64, 64,
        8, 131072LL, 1, 0LL,
        64, -1048576LL, 8, 131072LL,
        1, 4096LL, 1, 0LL,
        nullptr, 1, nullptr, nullptr, 0);

    // GQ = WqT^T WqT, GW = WkT^T WkT   (64x64, K=512)
    gemm_tn<64, 64, 16, 4, 4, 1, false, false, float, float><<<dim3(1, 1, 1), 256, 0, stream>>>(
        WqT, WqT, GQ, 512, 64, 64, 64,
        1, 0LL, 1, 0LL,  1, 0LL, 1, 0LL,  1, 0LL, 1, 0LL,
        nullptr, 1, nullptr, nullptr, 0);
    gemm_tn<64, 64, 16, 4, 4, 1, false, false, float, float><<<dim3(1, 1, 1), 256, 0, stream>>>(
        WkT, WkT, GW, 512, 64, 64, 64,
        1, 0LL, 1, 0LL,  1, 0LL, 1, 0LL,  1, 0LL, 1, 0LL,
        nullptr, 1, nullptr, nullptr, 0);

    stats2_k<<<128, 256, 0, stream>>>(G, GQ, GW, wqs, wks, sums);
    fin_k<<<1, 16, 0, stream>>>(sums, r);

    // E_T[pair][c'][i] = sum_c G[c][c'] * Wq[c][i]
    gemm_tn<64, 64, 16, 4, 4, 1, false, false, float, float><<<dim3(8, 1, 128), 256, 0, stream>>>(
        G, Wq, E_T, 64, 64, 512, 512,
        1, 4096LL, 1, 0LL,  1, 0LL, 1, 0LL,  1, 32768LL, 1, 0LL,
        nullptr, 1, nullptr, nullptr, 0);

    // expS[d,b][i][b'*512+ch] = exp(r * sum_c' E_T[c'][i]*Wk[c'][ch]) (fp16)
    // fused fp32 rowsums -> rs
    gemm_tn<128, 128, 16, 8, 8, 1, true, false, float, __half><<<dim3(4, 4, 128), 256, 0, stream>>>(
        E_T, Wk, expS, 64, 512, 512, 4096,
        1, 32768LL, 1, 0LL,
        1, 0LL, 1, 0LL,
        8, 2097152LL, 8, 512LL,
        r, 8, rs, nullptr, 0);

    // U2[d,b][j][o] = sum_i expS[i][j] * Wo[i][o]/rs[i]   (fp16 A)
    gemm_tn<128, 64, 32, 8, 4, 1, false, true, __half, float><<<dim3(1, 32, 16), 256, 0, stream>>>(
        expS, Wo, U2, 512, 4096, 64, 64,
        1, 2097152LL, 1, 0LL,
        1, 0LL, 1, 0LL,
        1, 262144LL, 1, 0LL,
        nullptr, 1, nullptr, rs, 512);

    // Z[d,b,b'][c][o] = sum_ch WvT[ch][c] * U2[b'*512+ch][o]
    gemm_tn<64, 64, 16, 4, 4, 1, false, false, float, float><<<dim3(1, 1, 128), 256, 0, stream>>>(
        WvT, U2, Zst, 512, 64, 64, 64,
        1, 0LL, 1, 0LL,
        8, 262144LL, 8, 32768LL,
        1, 4096LL, 1, 0LL,
        nullptr, 1, nullptr, nullptr, 0);

    // out[d*8+b][n][c] = sum_{b',c} XT2_kv[b'*64+c][n] * Zst[b'*64+c][o]
    gemm_tn<64, 64, 16, 4, 4, 1, false, false, float, float><<<dim3(1, 32, 16), 256, 0, stream>>>(
        XT2 + 1048576, Zst, out, 512, 2048, 64, 64,
        8, -1048576LL, 1, 0LL,
        1, 32768LL, 1, 0LL,
        1, 131072LL, 1, 0LL,
        nullptr, 1, nullptr, nullptr, 0);
}

// Round 6
// 378.764 us; speedup vs baseline: 10.0099x; 1.2116x over previous
//
#include <hip/hip_runtime.h>
#include <hip/hip_fp16.h>

#define EPS 1e-5f

typedef __attribute__((ext_vector_type(8))) _Float16 half8;
typedef __attribute__((ext_vector_type(4))) float float4v;

// ---------------------------------------------------------------------------
// Generalized batched TN GEMM: C[m][n] = sum_k A[k][m] * B[k][n]
// Offsets per z:  off = (z/div)*bsd + (z%mod)*bsm  (element units)
// KS>1: split-K, atomicAdd into pre-zeroed C. grid.y = Mtiles*KS.
// EXPSM: epilogue writes exp(r*acc) as TC (fp16 ok), atomicAdds fp32 row
//        sums into rsPtr[(z/rDiv)*512 + row]. Requires BN/TN==16.
// ---------------------------------------------------------------------------
template<int BM, int BN, int BK, int TM, int TN, int KS, bool EXPSM,
         typename TA, typename TC>
__global__ __launch_bounds__((BM/TM)*(BN/TN))
void gemm_tn(const TA* __restrict__ A, const float* __restrict__ B,
             TC* __restrict__ C, int K,
             int lda, int ldb, int ldc,
             int divA, long long bsAd, int modA, long long bsAm,
             int divB, long long bsBd, int modB, long long bsBm,
             int divC, long long bsCd, int modC, long long bsCm,
             const float* __restrict__ rPtr, int rDiv, float* __restrict__ rsPtr)
{
    constexpr int T  = (BM/TM)*(BN/TN);
    constexpr int HM = TM/2, HN = TN/2;
    __shared__ float As[BK][BM];
    __shared__ float Bs[BK][BN];

    const int tid = threadIdx.x;
    const int z = blockIdx.z;
    const int mtile = blockIdx.y / KS;
    const int ks = blockIdx.y % KS;
    const int n0 = blockIdx.x * BN;
    const int m0 = mtile * BM;
    A += (long long)(z / divA) * bsAd + (long long)(z % modA) * bsAm;
    B += (long long)(z / divB) * bsBd + (long long)(z % modB) * bsBm;
    C += (long long)(z / divC) * bsCd + (long long)(z % modC) * bsCm;

    const int tx = tid % (BN/TN);
    const int ty = tid / (BN/TN);

    float acc[TM][TN] = {};

    const int kc = K / KS;
    const int kBeg = ks * kc;

    for (int k0 = kBeg; k0 < kBeg + kc; k0 += BK) {
#pragma unroll
        for (int idx = tid * 4; idx < BK * BM; idx += T * 4) {
            int rr = idx / BM, cc = idx % BM;
            if constexpr (sizeof(TA) == 2) {
                const __half* Ah = (const __half*)(A + (long long)(k0 + rr) * lda + m0 + cc);
                float2 f0 = __half22float2(*(const __half2*)Ah);
                float2 f1 = __half22float2(*(const __half2*)(Ah + 2));
                As[rr][cc] = f0.x; As[rr][cc + 1] = f0.y;
                As[rr][cc + 2] = f1.x; As[rr][cc + 3] = f1.y;
            } else {
                *(float4*)&As[rr][cc] = *(const float4*)(A + (long long)(k0 + rr) * lda + m0 + cc);
            }
        }
#pragma unroll
        for (int idx = tid * 4; idx < BK * BN; idx += T * 4) {
            int rr = idx / BN, cc = idx % BN;
            *(float4*)&Bs[rr][cc] = *(const float4*)(B + (long long)(k0 + rr) * ldb + n0 + cc);
        }
        __syncthreads();
#pragma unroll
        for (int kk = 0; kk < BK; kk++) {
            float a[TM], b[TN];
#pragma unroll
            for (int u = 0; u < HM; u++) {
                a[u]      = As[kk][ty * HM + u];
                a[HM + u] = As[kk][BM / 2 + ty * HM + u];
            }
#pragma unroll
            for (int v = 0; v < HN; v++) {
                b[v]      = Bs[kk][tx * HN + v];
                b[HN + v] = Bs[kk][BN / 2 + tx * HN + v];
            }
#pragma unroll
            for (int u = 0; u < TM; u++)
#pragma unroll
                for (int v = 0; v < TN; v++)
                    acc[u][v] += a[u] * b[v];
        }
        __syncthreads();
    }

    if constexpr (EXPSM) {
        const float rv = rPtr[z / rDiv];
        const long long rsBase = (long long)(z / rDiv) * 512 + m0;
#pragma unroll
        for (int u = 0; u < TM; u++) {
            int rl = (u < HM) ? ty * HM + u : BM / 2 + ty * HM + (u - HM);
            float ev[TN];
            float p = 0.f;
#pragma unroll
            for (int v = 0; v < TN; v++) { ev[v] = __expf(rv * acc[u][v]); p += ev[v]; }
            TC* cr = C + (long long)(m0 + rl) * ldc + n0;
            if constexpr (sizeof(TC) == 2) {
                __half2* c0 = (__half2*)(cr + tx * HN);
                c0[0] = __floats2half2_rn(ev[0], ev[1]);
                c0[1] = __floats2half2_rn(ev[2], ev[3]);
                __half2* c1 = (__half2*)(cr + BN / 2 + tx * HN);
                c1[0] = __floats2half2_rn(ev[4], ev[5]);
                c1[1] = __floats2half2_rn(ev[6], ev[7]);
            } else {
                *(float4*)(cr + tx * HN) = make_float4(ev[0], ev[1], ev[2], ev[3]);
                *(float4*)(cr + BN / 2 + tx * HN) = make_float4(ev[4], ev[5], ev[6], ev[7]);
            }
#pragma unroll
            for (int off = 8; off; off >>= 1) p += __shfl_down(p, off, 16);
            if (tx == 0) atomicAdd(&rsPtr[rsBase + rl], p);
        }
    } else if constexpr (KS > 1) {
#pragma unroll
        for (int u = 0; u < TM; u++) {
            int rl = (u < HM) ? ty * HM + u : BM / 2 + ty * HM + (u - HM);
#pragma unroll
            for (int v = 0; v < TN; v++) {
                int cl = (v < HN) ? tx * HN + v : BN / 2 + tx * HN + (v - HN);
                atomicAdd(&C[(long long)(m0 + rl) * ldc + n0 + cl], acc[u][v]);
            }
        }
    } else {
#pragma unroll
        for (int u = 0; u < TM; u++) {
            int rl = (u < HM) ? ty * HM + u : BM / 2 + ty * HM + (u - HM);
            TC* cr = C + (long long)(m0 + rl) * ldc + n0;
            if constexpr (HN == 4) {
                *(float4*)(cr + tx * HN) = make_float4(acc[u][0], acc[u][1], acc[u][2], acc[u][3]);
                *(float4*)(cr + BN / 2 + tx * HN) = make_float4(acc[u][4], acc[u][5], acc[u][6], acc[u][7]);
            } else {
#pragma unroll
                for (int v = 0; v < HN; v++) {
                    cr[tx * HN + v] = acc[u][v];
                    cr[BN / 2 + tx * HN + v] = acc[u][HN + v];
                }
            }
        }
    }
}

// ---------------------------------------------------------------------------
// MFMA U2:  U2[z][j][o] = (1/4096) * sum_i expS[z][i][j] * Wo16T[z][o][i]
// expS fp16 (A), Wo16T fp16 (B, pre-scaled by 4096/rs), f32 accumulate.
// block 256 thr (4 waves), tile 128 j x 64 o, BK=64 i. grid (32, 1, 16).
// v_mfma_f32_16x16x32_f16: A[m=lane&15][k=quad*8+t], B[k=quad*8+t][n=lane&15],
// D col=lane&15, row=quad*4+reg.
// ---------------------------------------------------------------------------
__global__ __launch_bounds__(256)
void mfma_u2(const __half* __restrict__ expS, const __half* __restrict__ Wo16T,
             float* __restrict__ U2)
{
    __shared__ __half As[64][136];  // [i][j] pad keeps 16B alignment
    __shared__ __half Bs[64][72];   // [o][i]
    const int tid = threadIdx.x;
    const int z = blockIdx.z;
    const int j0 = blockIdx.x * 128;
    const __half* Ez = expS + (long long)z * 2097152;
    const __half* Bz = Wo16T + z * 32768;

    const int lane = tid & 63;
    const int w = tid >> 6;
    const int q = lane >> 4;
    const int l16 = lane & 15;

    float4v acc[2][4];
#pragma unroll
    for (int a = 0; a < 2; a++)
#pragma unroll
        for (int b = 0; b < 4; b++) acc[a][b] = (float4v)0.f;

    const int srow = tid >> 4;        // 0..15
    const int scol = (tid & 15) * 8;  // 0..120

    for (int i0 = 0; i0 < 512; i0 += 64) {
#pragma unroll
        for (int rr = 0; rr < 4; rr++) {
            int i = srow + rr * 16;
            *(half8*)&As[i][scol] = *(const half8*)(Ez + (long long)(i0 + i) * 4096 + j0 + scol);
        }
        {
            int o = tid >> 2;
            int c8 = (tid & 3) * 16;
            *(half8*)&Bs[o][c8]     = *(const half8*)(Bz + o * 512 + i0 + c8);
            *(half8*)&Bs[o][c8 + 8] = *(const half8*)(Bz + o * 512 + i0 + c8 + 8);
        }
        __syncthreads();
#pragma unroll
        for (int kc = 0; kc < 64; kc += 32) {
            half8 bf[4];
#pragma unroll
            for (int ot = 0; ot < 4; ot++)
                bf[ot] = *(const half8*)&Bs[ot * 16 + l16][kc + q * 8];
#pragma unroll
            for (int jt = 0; jt < 2; jt++) {
                half8 af;
#pragma unroll
                for (int t = 0; t < 8; t++)
                    af[t] = As[kc + q * 8 + t][w * 32 + jt * 16 + l16];
#pragma unroll
                for (int ot = 0; ot < 4; ot++)
                    acc[jt][ot] = __builtin_amdgcn_mfma_f32_16x16x32_f16(af, bf[ot], acc[jt][ot], 0, 0, 0);
            }
        }
        __syncthreads();
    }

    const float sc = 1.f / 4096.f;
    float* Uz = U2 + (long long)z * 262144;
#pragma unroll
    for (int jt = 0; jt < 2; jt++)
#pragma unroll
        for (int ot = 0; ot < 4; ot++)
#pragma unroll
            for (int t = 0; t < 4; t++) {
                int j = j0 + w * 32 + jt * 16 + q * 4 + t;
                int o = ot * 16 + l16;
                Uz[j * 64 + o] = acc[jt][ot][t] * sc;
            }
}

// ---------------------------------------------------------------------------
// Wo16T[z][o][i] = fp16(Wo[i][o] * 4096 / rs[z][i]).  grid 16, block 256.
// ---------------------------------------------------------------------------
__global__ __launch_bounds__(256)
void woprep_k(const float* __restrict__ Wo, const float* __restrict__ rs,
              __half* __restrict__ Wo16T)
{
    const int z = blockIdx.x;
    for (int idx = threadIdx.x; idx < 32768; idx += 256) {
        int o = idx >> 9, i = idx & 511;
        float v = Wo[i * 64 + o] * 4096.0f / rs[z * 512 + i];
        Wo16T[z * 32768 + idx] = __float2half(v);
    }
}

// ---------------------------------------------------------------------------
// 64x64 LDS tile transpose
// ---------------------------------------------------------------------------
__global__ __launch_bounds__(256)
void transpose_k(const float* __restrict__ in, float* __restrict__ out,
                 int rows, int cols, int ldin, int ldout,
                 long long bsIn, long long bsOut)
{
    __shared__ float t[64][65];
    in += blockIdx.z * bsIn;
    out += blockIdx.z * bsOut;
    const int c0 = blockIdx.x * 64, r0 = blockIdx.y * 64;
    const int c = threadIdx.x & 63, r4 = threadIdx.x >> 6;
#pragma unroll
    for (int rr = r4; rr < 64; rr += 4)
        t[rr][c] = in[(long long)(r0 + rr) * ldin + c0 + c];
    __syncthreads();
#pragma unroll
    for (int rr = r4; rr < 64; rr += 4)
        out[(long long)(c0 + rr) * ldout + r0 + c] = t[c][rr];
}

// ---------------------------------------------------------------------------
// Row sums of the 64x512 weight matrices.
// ---------------------------------------------------------------------------
__global__ __launch_bounds__(256)
void wsum_k(const float* __restrict__ Wq, const float* __restrict__ Wk,
            float* __restrict__ wqs, float* __restrict__ wks)
{
    const float* W = blockIdx.x ? Wk : Wq;
    float* o = blockIdx.x ? wks : wqs;
    __shared__ float acc[64];
    if (threadIdx.x < 64) acc[threadIdx.x] = 0.f;
    __syncthreads();
    for (int idx = threadIdx.x * 4; idx < 32768; idx += 1024) {
        float4 v = *(const float4*)(W + idx);
        atomicAdd(&acc[idx >> 9], v.x + v.y + v.z + v.w);
    }
    __syncthreads();
    if (threadIdx.x < 64) o[threadIdx.x] = acc[threadIdx.x];
}

// ---------------------------------------------------------------------------
// Analytic InstanceNorm stats from 64x64 Grams:
//   s1_pair = wqs^T G_pair wks ; s2_pair = <GQ*G_pair, G_pair*GW>
// ---------------------------------------------------------------------------
__global__ __launch_bounds__(256)
void stats2_k(const float* __restrict__ G, const float* __restrict__ GQ,
              const float* __restrict__ GW, const float* __restrict__ wqs,
              const float* __restrict__ wks, float* __restrict__ sums)
{
    __shared__ float Gs[64][68], GQs[64][68], GWs[64][68];
    const int tid = threadIdx.x;
    const float* Gp = G + (long long)blockIdx.x * 4096;
    for (int f = tid * 4; f < 4096; f += 1024) {
        int rr = f >> 6, cc = f & 63;
        *(float4*)&Gs[rr][cc]  = *(const float4*)(Gp + f);
        *(float4*)&GQs[rr][cc] = *(const float4*)(GQ + f);
        *(float4*)&GWs[rr][cc] = *(const float4*)(GW + f);
    }
    __syncthreads();
    const int r = tid >> 2;
    const int c0 = (tid & 3) * 16;
    float p1[16] = {}, p2[16] = {};
    for (int k = 0; k < 64; k++) {
        float gq = GQs[r][k], g = Gs[r][k];
#pragma unroll
        for (int j = 0; j < 16; j++) {
            p1[j] += gq * Gs[k][c0 + j];
            p2[j] += g  * GWs[k][c0 + j];
        }
    }
    float s2 = 0.f;
#pragma unroll
    for (int j = 0; j < 16; j++) s2 += p1[j] * p2[j];
    float s1 = 0.f;
    const float wq = wqs[r];
#pragma unroll
    for (int j = 0; j < 16; j++) s1 += wq * Gs[r][c0 + j] * wks[c0 + j];

    const int lane = tid & 63, w = tid >> 6;
#pragma unroll
    for (int off = 32; off; off >>= 1) {
        s1 += __shfl_down(s1, off, 64);
        s2 += __shfl_down(s2, off, 64);
    }
    __shared__ float r1[4], r2[4];
    if (lane == 0) { r1[w] = s1; r2[w] = s2; }
    __syncthreads();
    if (tid == 0) {
        atomicAdd(&sums[(blockIdx.x >> 3) * 2],     r1[0] + r1[1] + r1[2] + r1[3]);
        atomicAdd(&sums[(blockIdx.x >> 3) * 2 + 1], r2[0] + r2[1] + r2[2] + r2[3]);
    }
}

__global__ void fin_k(const float* __restrict__ sums, float* __restrict__ r)
{
    const int t = threadIdx.x;  // 16
    const float inv = 1.f / 2097152.f;
    float mu  = sums[2 * t] * inv;
    float var = sums[2 * t + 1] * inv - mu * mu;
    r[t] = rsqrtf(var + EPS);
}

// ---------------------------------------------------------------------------
// Workspace (floats):
//   XT2 @0:2097152 | WkT @2097152 | WqT @2129920 | WvT @2162688
//   zeroed: G @2195456:524288 | rs @2719744:8192 | sums @2727936:32
//           GW @2727968:4096 | GQ @2732064:4096   (memset 540704)
//   r @2736160:16 | wqs @2736176:64 | wks @2736240:64
//   E_T @2736304:4194304 (U2 aliases after expS gemm consumes E_T)
//   Wo16T @6930608: 524288 halves (262144 float slots)
//   expS @7192752: 33554432 halves; Zst aliases its head after mfma_u2
// ---------------------------------------------------------------------------
extern "C" void kernel_launch(void* const* d_in, const int* in_sizes, int n_in,
                              void* d_out, int out_size, void* d_ws, size_t ws_size,
                              hipStream_t stream)
{
    const float* emb = (const float*)d_in[0];
    const float* Wq  = (const float*)d_in[1];
    const float* Wk  = (const float*)d_in[2];
    const float* Wv  = (const float*)d_in[3];
    const float* Wo  = (const float*)d_in[4];
    float* out = (float*)d_out;
    float* ws  = (float*)d_ws;

    float* XT2   = ws;
    float* WkT   = ws + 2097152;
    float* WqT   = ws + 2129920;
    float* WvT   = ws + 2162688;
    float* G     = ws + 2195456;
    float* rs    = ws + 2719744;
    float* sums  = ws + 2727936;
    float* GW    = ws + 2727968;
    float* GQ    = ws + 2732064;
    float* r     = ws + 2736160;
    float* wqs   = ws + 2736176;
    float* wks   = ws + 2736240;
    float* E_T   = ws + 2736304;
    __half* Wo16T = (__half*)(ws + 6930608);
    __half* expS  = (__half*)(ws + 7192752);
    float* U2    = E_T;            // alias (E_T dead after expS gemm)
    float* Zst   = ws + 7192752;   // alias expS head (dead after mfma_u2)

    transpose_k<<<dim3(1, 32, 16), 256, 0, stream>>>(emb, XT2, 2048, 64, 64, 2048, 131072LL, 131072LL);
    transpose_k<<<dim3(8, 1, 1), 256, 0, stream>>>(Wk, WkT, 64, 512, 512, 64, 0, 0);
    transpose_k<<<dim3(8, 1, 1), 256, 0, stream>>>(Wq, WqT, 64, 512, 512, 64, 0, 0);
    transpose_k<<<dim3(8, 1, 1), 256, 0, stream>>>(Wv, WvT, 64, 512, 512, 64, 0, 0);
    hipMemsetAsync(G, 0, 540704 * sizeof(float), stream);  // G + rs + sums + GW + GQ
    wsum_k<<<2, 256, 0, stream>>>(Wq, Wk, wqs, wks);

    // G[z=d*64+b*8+b'] = emb_q[d,b]^T @ emb_kv[d,b']   K=2048 split-K4
    gemm_tn<64, 64, 16, 4, 4, 4, false, float, float><<<dim3(1, 4, 128), 256, 0, stream>>>(
        emb, emb + 1048576, G, 2048, 64, 64, 64,
        8, 131072LL, 1, 0LL,
        64, -1048576LL, 8, 131072LL,
        1, 4096LL, 1, 0LL,
        nullptr, 1, nullptr);

    // GW (z=0, from WkT) and GQ (z=1, from WqT): 64x64, K=512, split-K8 batched
    gemm_tn<64, 64, 16, 4, 4, 8, false, float, float><<<dim3(1, 8, 2), 256, 0, stream>>>(
        WkT, WkT, GW, 512, 64, 64, 64,
        1, 0LL, 2, 32768LL,
        1, 0LL, 2, 32768LL,
        1, 0LL, 2, 4096LL,
        nullptr, 1, nullptr);

    stats2_k<<<128, 256, 0, stream>>>(G, GQ, GW, wqs, wks, sums);
    fin_k<<<1, 16, 0, stream>>>(sums, r);

    // E_T[pair][c'][i] = sum_c G[c][c'] * Wq[c][i]
    gemm_tn<64, 64, 16, 4, 4, 1, false, float, float><<<dim3(8, 1, 128), 256, 0, stream>>>(
        G, Wq, E_T, 64, 64, 512, 512,
        1, 4096LL, 1, 0LL,  1, 0LL, 1, 0LL,  1, 32768LL, 1, 0LL,
        nullptr, 1, nullptr);

    // expS[d,b][i][b'*512+ch] = exp(r * sum_c' E_T[c'][i]*Wk[c'][ch]) (fp16)
    gemm_tn<128, 128, 16, 8, 8, 1, true, float, __half><<<dim3(4, 4, 128), 256, 0, stream>>>(
        E_T, Wk, expS, 64, 512, 512, 4096,
        1, 32768LL, 1, 0LL,
        1, 0LL, 1, 0LL,
        8, 2097152LL, 8, 512LL,
        r, 8, rs);

    // Wo16T[z][o][i] = fp16(Wo[i][o]*4096/rs[z][i])
    woprep_k<<<16, 256, 0, stream>>>(Wo, rs, Wo16T);

    // U2[z][j][o] = (1/4096) sum_i expS[i][j] * Wo16T[o][i]   (MFMA f16)
    mfma_u2<<<dim3(32, 1, 16), 256, 0, stream>>>(expS, Wo16T, U2);

    // Z[d,b,b'][c][o] = sum_ch WvT[ch][c] * U2[b'*512+ch][o]
    gemm_tn<64, 64, 16, 4, 4, 1, false, float, float><<<dim3(1, 1, 128), 256, 0, stream>>>(
        WvT, U2, Zst, 512, 64, 64, 64,
        1, 0LL, 1, 0LL,
        8, 262144LL, 8, 32768LL,
        1, 4096LL, 1, 0LL,
        nullptr, 1, nullptr);

    // out[d*8+b][n][c] = sum_{b',c} XT2_kv[b'*64+c][n] * Zst[b'*64+c][o]
    gemm_tn<64, 64, 16, 4, 4, 1, false, float, float><<<dim3(1, 32, 16), 256, 0, stream>>>(
        XT2 + 1048576, Zst, out, 512, 2048, 64, 64,
        8, -1048576LL, 1, 0LL,
        1, 32768LL, 1, 0LL,
        1, 131072LL, 1, 0LL,
        nullptr, 1, nullptr);
}

// Round 7
// 340.091 us; speedup vs baseline: 11.1482x; 1.1137x over previous
//
#include <hip/hip_runtime.h>
#include <hip/hip_fp16.h>

#define EPS 1e-5f

typedef __attribute__((ext_vector_type(8))) _Float16 half8;
typedef __attribute__((ext_vector_type(4))) float float4v;

// ---------------------------------------------------------------------------
// Generalized batched TN GEMM: C[m][n] = sum_k A[k][m] * B[k][n]
// Offsets per z:  off = (z/div)*bsd + (z%mod)*bsm  (element units of the ptr)
// KS>1: split-K, atomicAdd into pre-zeroed C. grid.y = Mtiles*KS.
// TC=__half supported on the plain-store path (scalar converts).
// ---------------------------------------------------------------------------
template<int BM, int BN, int BK, int TM, int TN, int KS, typename TA, typename TC>
__global__ __launch_bounds__((BM/TM)*(BN/TN))
void gemm_tn(const TA* __restrict__ A, const float* __restrict__ B,
             TC* __restrict__ C, int K,
             int lda, int ldb, int ldc,
             int divA, long long bsAd, int modA, long long bsAm,
             int divB, long long bsBd, int modB, long long bsBm,
             int divC, long long bsCd, int modC, long long bsCm)
{
    constexpr int T  = (BM/TM)*(BN/TN);
    constexpr int HM = TM/2, HN = TN/2;
    __shared__ float As[BK][BM];
    __shared__ float Bs[BK][BN];

    const int tid = threadIdx.x;
    const int z = blockIdx.z;
    const int mtile = blockIdx.y / KS;
    const int ks = blockIdx.y % KS;
    const int n0 = blockIdx.x * BN;
    const int m0 = mtile * BM;
    A += (long long)(z / divA) * bsAd + (long long)(z % modA) * bsAm;
    B += (long long)(z / divB) * bsBd + (long long)(z % modB) * bsBm;
    C += (long long)(z / divC) * bsCd + (long long)(z % modC) * bsCm;

    const int tx = tid % (BN/TN);
    const int ty = tid / (BN/TN);

    float acc[TM][TN] = {};

    const int kc = K / KS;
    const int kBeg = ks * kc;

    for (int k0 = kBeg; k0 < kBeg + kc; k0 += BK) {
#pragma unroll
        for (int idx = tid * 4; idx < BK * BM; idx += T * 4) {
            int rr = idx / BM, cc = idx % BM;
            *(float4*)&As[rr][cc] = *(const float4*)(A + (long long)(k0 + rr) * lda + m0 + cc);
        }
#pragma unroll
        for (int idx = tid * 4; idx < BK * BN; idx += T * 4) {
            int rr = idx / BN, cc = idx % BN;
            *(float4*)&Bs[rr][cc] = *(const float4*)(B + (long long)(k0 + rr) * ldb + n0 + cc);
        }
        __syncthreads();
#pragma unroll
        for (int kk = 0; kk < BK; kk++) {
            float a[TM], b[TN];
#pragma unroll
            for (int u = 0; u < HM; u++) {
                a[u]      = As[kk][ty * HM + u];
                a[HM + u] = As[kk][BM / 2 + ty * HM + u];
            }
#pragma unroll
            for (int v = 0; v < HN; v++) {
                b[v]      = Bs[kk][tx * HN + v];
                b[HN + v] = Bs[kk][BN / 2 + tx * HN + v];
            }
#pragma unroll
            for (int u = 0; u < TM; u++)
#pragma unroll
                for (int v = 0; v < TN; v++)
                    acc[u][v] += a[u] * b[v];
        }
        __syncthreads();
    }

    if constexpr (KS > 1) {
#pragma unroll
        for (int u = 0; u < TM; u++) {
            int rl = (u < HM) ? ty * HM + u : BM / 2 + ty * HM + (u - HM);
#pragma unroll
            for (int v = 0; v < TN; v++) {
                int cl = (v < HN) ? tx * HN + v : BN / 2 + tx * HN + (v - HN);
                atomicAdd(&C[(long long)(m0 + rl) * ldc + n0 + cl], acc[u][v]);
            }
        }
    } else {
#pragma unroll
        for (int u = 0; u < TM; u++) {
            int rl = (u < HM) ? ty * HM + u : BM / 2 + ty * HM + (u - HM);
            TC* cr = C + (long long)(m0 + rl) * ldc + n0;
            if constexpr (sizeof(TC) == 2) {
#pragma unroll
                for (int v = 0; v < HN; v++) {
                    cr[tx * HN + v]          = __float2half(acc[u][v]);
                    cr[BN / 2 + tx * HN + v] = __float2half(acc[u][HN + v]);
                }
            } else if constexpr (HN == 4) {
                *(float4*)(cr + tx * HN) = make_float4(acc[u][0], acc[u][1], acc[u][2], acc[u][3]);
                *(float4*)(cr + BN / 2 + tx * HN) = make_float4(acc[u][4], acc[u][5], acc[u][6], acc[u][7]);
            } else {
#pragma unroll
                for (int v = 0; v < HN; v++) {
                    cr[tx * HN + v] = acc[u][v];
                    cr[BN / 2 + tx * HN + v] = acc[u][HN + v];
                }
            }
        }
    }
}

// ---------------------------------------------------------------------------
// MFMA expS:  expS[db][i][b'*512+ch] = exp(r[db] * sum_c' E16[z][i][c'] *
//             WkT16[ch][c'])   (fp16 out) with fused fp32 rowsums -> rs.
// E16: [pair z][512 i][64 c'] fp16 (A-operand native: row-contig in k).
// WkT16: [512 ch][64 c'] fp16 (B-operand native).
// grid (4 ch-tiles, 4 i-tiles, 128 pairs), block 256 (4 waves).
// Wave w: i-rows w*32..w*32+31 (2 m-tiles), all 128 ch (8 n-tiles).
// ---------------------------------------------------------------------------
__global__ __launch_bounds__(256)
void mfma_exps(const __half* __restrict__ E16, const __half* __restrict__ WkT16,
               const float* __restrict__ rPtr, __half* __restrict__ expS,
               float* __restrict__ rs)
{
    __shared__ __half Es[128][72];
    __shared__ __half Ws[128][72];
    const int tid = threadIdx.x;
    const int z = blockIdx.z;          // pair = (d*8+b)*8 + b'
    const int i0 = blockIdx.y * 128;
    const int ch0 = blockIdx.x * 128;
    const int db = z >> 3;
    const int bp = z & 7;
    const __half* Ez = E16 + (long long)z * 32768;

#pragma unroll
    for (int it = 0; it < 4; it++) {
        int e = tid + it * 256;        // 0..1023
        int row = e >> 3, c8 = (e & 7) * 8;
        *(half8*)&Es[row][c8] = *(const half8*)(Ez + (long long)(i0 + row) * 64 + c8);
        *(half8*)&Ws[row][c8] = *(const half8*)(WkT16 + (long long)(ch0 + row) * 64 + c8);
    }
    __syncthreads();

    const int lane = tid & 63;
    const int w = tid >> 6;
    const int q = lane >> 4;
    const int l16 = lane & 15;

    float4v acc[2][8];
#pragma unroll
    for (int a = 0; a < 2; a++)
#pragma unroll
        for (int b = 0; b < 8; b++) acc[a][b] = (float4v)0.f;

#pragma unroll
    for (int kc = 0; kc < 64; kc += 32) {
        half8 af[2], bf[8];
#pragma unroll
        for (int mt = 0; mt < 2; mt++)
            af[mt] = *(const half8*)&Es[w * 32 + mt * 16 + l16][kc + q * 8];
#pragma unroll
        for (int nt = 0; nt < 8; nt++)
            bf[nt] = *(const half8*)&Ws[nt * 16 + l16][kc + q * 8];
#pragma unroll
        for (int mt = 0; mt < 2; mt++)
#pragma unroll
            for (int nt = 0; nt < 8; nt++)
                acc[mt][nt] = __builtin_amdgcn_mfma_f32_16x16x32_f16(af[mt], bf[nt], acc[mt][nt], 0, 0, 0);
    }

    const float rv = rPtr[db];
    __half* Cz = expS + (long long)db * 2097152 + bp * 512 + ch0;
    float* rsb = rs + db * 512 + i0 + w * 32;
#pragma unroll
    for (int mt = 0; mt < 2; mt++) {
#pragma unroll
        for (int t = 0; t < 4; t++) {
            const int irow = mt * 16 + q * 4 + t;
            const long long rowOff = (long long)(i0 + w * 32 + irow) * 4096;
            float p = 0.f;
#pragma unroll
            for (int nt = 0; nt < 8; nt++) {
                float v = __expf(rv * acc[mt][nt][t]);
                p += v;
                Cz[rowOff + nt * 16 + l16] = __float2half(v);
            }
            p += __shfl_xor(p, 1, 16);
            p += __shfl_xor(p, 2, 16);
            p += __shfl_xor(p, 4, 16);
            p += __shfl_xor(p, 8, 16);
            if (l16 == 0) atomicAdd(&rsb[irow], p);
        }
    }
}

// ---------------------------------------------------------------------------
// MFMA U2:  U2[z][j][o] = (1/4096) * sum_i expS[z][i][j] * Wo16T[z][o][i]
// As tile XOR-swizzled (granule 16, key (row>>3)&3 == q at read) to kill the
// structural 4-way quad conflict on column reads.
// ---------------------------------------------------------------------------
__global__ __launch_bounds__(256)
void mfma_u2(const __half* __restrict__ expS, const __half* __restrict__ Wo16T,
             float* __restrict__ U2)
{
    __shared__ __half As[64][136];  // [i][j], 16B-aligned rows, XOR-swizzled cols
    __shared__ __half Bs[64][72];   // [o][i]
    const int tid = threadIdx.x;
    const int z = blockIdx.z;
    const int j0 = blockIdx.x * 128;
    const __half* Ez = expS + (long long)z * 2097152;
    const __half* Bz = Wo16T + z * 32768;

    const int lane = tid & 63;
    const int w = tid >> 6;
    const int q = lane >> 4;
    const int l16 = lane & 15;

    float4v acc[2][4];
#pragma unroll
    for (int a = 0; a < 2; a++)
#pragma unroll
        for (int b = 0; b < 4; b++) acc[a][b] = (float4v)0.f;

    const int srow = tid >> 4;        // 0..15
    const int scol = (tid & 15) * 8;  // 0..120

    for (int i0 = 0; i0 < 512; i0 += 64) {
#pragma unroll
        for (int rr = 0; rr < 4; rr++) {
            int i = srow + rr * 16;
            int cph = scol ^ (((i >> 3) & 3) << 4);
            *(half8*)&As[i][cph] = *(const half8*)(Ez + (long long)(i0 + i) * 4096 + j0 + scol);
        }
        {
            int o = tid >> 2;
            int c8 = (tid & 3) * 16;
            *(half8*)&Bs[o][c8]     = *(const half8*)(Bz + o * 512 + i0 + c8);
            *(half8*)&Bs[o][c8 + 8] = *(const half8*)(Bz + o * 512 + i0 + c8 + 8);
        }
        __syncthreads();
#pragma unroll
        for (int kc = 0; kc < 64; kc += 32) {
            half8 bf[4];
#pragma unroll
            for (int ot = 0; ot < 4; ot++)
                bf[ot] = *(const half8*)&Bs[ot * 16 + l16][kc + q * 8];
#pragma unroll
            for (int jt = 0; jt < 2; jt++) {
                const int cph = (w * 32 + jt * 16 + l16) ^ (q << 4);
                half8 af;
#pragma unroll
                for (int t = 0; t < 8; t++)
                    af[t] = As[kc + q * 8 + t][cph];
#pragma unroll
                for (int ot = 0; ot < 4; ot++)
                    acc[jt][ot] = __builtin_amdgcn_mfma_f32_16x16x32_f16(af, bf[ot], acc[jt][ot], 0, 0, 0);
            }
        }
        __syncthreads();
    }

    const float sc = 1.f / 4096.f;
    float* Uz = U2 + (long long)z * 262144;
#pragma unroll
    for (int jt = 0; jt < 2; jt++)
#pragma unroll
        for (int ot = 0; ot < 4; ot++)
#pragma unroll
            for (int t = 0; t < 4; t++) {
                int j = j0 + w * 32 + jt * 16 + q * 4 + t;
                int o = ot * 16 + l16;
                Uz[j * 64 + o] = acc[jt][ot][t] * sc;
            }
}

// ---------------------------------------------------------------------------
// Wo16T[z][o][i] = fp16(Wo[i][o] * 4096 / rs[z][i]).  grid 16, block 256.
// ---------------------------------------------------------------------------
__global__ __launch_bounds__(256)
void woprep_k(const float* __restrict__ Wo, const float* __restrict__ rs,
              __half* __restrict__ Wo16T)
{
    const int z = blockIdx.x;
    for (int idx = threadIdx.x; idx < 32768; idx += 256) {
        int o = idx >> 9, i = idx & 511;
        float v = Wo[i * 64 + o] * 4096.0f / rs[z * 512 + i];
        Wo16T[z * 32768 + idx] = __float2half(v);
    }
}

// ---------------------------------------------------------------------------
// WkT16[ch][c'] = fp16(WkT[ch][c']).  grid 32, block 256.
// ---------------------------------------------------------------------------
__global__ __launch_bounds__(256)
void wk16_k(const float* __restrict__ WkT, __half* __restrict__ WkT16)
{
    int idx = blockIdx.x * 1024 + threadIdx.x * 4;
    float4 v = *(const float4*)(WkT + idx);
    WkT16[idx]     = __float2half(v.x);
    WkT16[idx + 1] = __float2half(v.y);
    WkT16[idx + 2] = __float2half(v.z);
    WkT16[idx + 3] = __float2half(v.w);
}

// ---------------------------------------------------------------------------
// 64x64 LDS tile transpose
// ---------------------------------------------------------------------------
__global__ __launch_bounds__(256)
void transpose_k(const float* __restrict__ in, float* __restrict__ out,
                 int rows, int cols, int ldin, int ldout,
                 long long bsIn, long long bsOut)
{
    __shared__ float t[64][65];
    in += blockIdx.z * bsIn;
    out += blockIdx.z * bsOut;
    const int c0 = blockIdx.x * 64, r0 = blockIdx.y * 64;
    const int c = threadIdx.x & 63, r4 = threadIdx.x >> 6;
#pragma unroll
    for (int rr = r4; rr < 64; rr += 4)
        t[rr][c] = in[(long long)(r0 + rr) * ldin + c0 + c];
    __syncthreads();
#pragma unroll
    for (int rr = r4; rr < 64; rr += 4)
        out[(long long)(c0 + rr) * ldout + r0 + c] = t[c][rr];
}

// ---------------------------------------------------------------------------
// Row sums of the 64x512 weight matrices.
// ---------------------------------------------------------------------------
__global__ __launch_bounds__(256)
void wsum_k(const float* __restrict__ Wq, const float* __restrict__ Wk,
            float* __restrict__ wqs, float* __restrict__ wks)
{
    const float* W = blockIdx.x ? Wk : Wq;
    float* o = blockIdx.x ? wks : wqs;
    __shared__ float acc[64];
    if (threadIdx.x < 64) acc[threadIdx.x] = 0.f;
    __syncthreads();
    for (int idx = threadIdx.x * 4; idx < 32768; idx += 1024) {
        float4 v = *(const float4*)(W + idx);
        atomicAdd(&acc[idx >> 9], v.x + v.y + v.z + v.w);
    }
    __syncthreads();
    if (threadIdx.x < 64) o[threadIdx.x] = acc[threadIdx.x];
}

// ---------------------------------------------------------------------------
// Analytic InstanceNorm stats from 64x64 Grams:
//   s1_pair = wqs^T G_pair wks ; s2_pair = <GQ*G_pair, G_pair*GW>
// ---------------------------------------------------------------------------
__global__ __launch_bounds__(256)
void stats2_k(const float* __restrict__ G, const float* __restrict__ GQ,
              const float* __restrict__ GW, const float* __restrict__ wqs,
              const float* __restrict__ wks, float* __restrict__ sums)
{
    __shared__ float Gs[64][68], GQs[64][68], GWs[64][68];
    const int tid = threadIdx.x;
    const float* Gp = G + (long long)blockIdx.x * 4096;
    for (int f = tid * 4; f < 4096; f += 1024) {
        int rr = f >> 6, cc = f & 63;
        *(float4*)&Gs[rr][cc]  = *(const float4*)(Gp + f);
        *(float4*)&GQs[rr][cc] = *(const float4*)(GQ + f);
        *(float4*)&GWs[rr][cc] = *(const float4*)(GW + f);
    }
    __syncthreads();
    const int r = tid >> 2;
    const int c0 = (tid & 3) * 16;
    float p1[16] = {}, p2[16] = {};
    for (int k = 0; k < 64; k++) {
        float gq = GQs[r][k], g = Gs[r][k];
#pragma unroll
        for (int j = 0; j < 16; j++) {
            p1[j] += gq * Gs[k][c0 + j];
            p2[j] += g  * GWs[k][c0 + j];
        }
    }
    float s2 = 0.f;
#pragma unroll
    for (int j = 0; j < 16; j++) s2 += p1[j] * p2[j];
    float s1 = 0.f;
    const float wq = wqs[r];
#pragma unroll
    for (int j = 0; j < 16; j++) s1 += wq * Gs[r][c0 + j] * wks[c0 + j];

    const int lane = tid & 63, w = tid >> 6;
#pragma unroll
    for (int off = 32; off; off >>= 1) {
        s1 += __shfl_down(s1, off, 64);
        s2 += __shfl_down(s2, off, 64);
    }
    __shared__ float r1[4], r2[4];
    if (lane == 0) { r1[w] = s1; r2[w] = s2; }
    __syncthreads();
    if (tid == 0) {
        atomicAdd(&sums[(blockIdx.x >> 3) * 2],     r1[0] + r1[1] + r1[2] + r1[3]);
        atomicAdd(&sums[(blockIdx.x >> 3) * 2 + 1], r2[0] + r2[1] + r2[2] + r2[3]);
    }
}

__global__ void fin_k(const float* __restrict__ sums, float* __restrict__ r)
{
    const int t = threadIdx.x;  // 16
    const float inv = 1.f / 2097152.f;
    float mu  = sums[2 * t] * inv;
    float var = sums[2 * t + 1] * inv - mu * mu;
    r[t] = rsqrtf(var + EPS);
}

// ---------------------------------------------------------------------------
// Workspace (float offsets):
//   XT2 @0:2097152 | WkT @2097152 | WqT @2129920 | WvT @2162688
//   zeroed block: G @2195456:524288 | rs @2719744:8192 | sums @2727936:32
//                 GW @2727968:4096 | GQ @2732064:4096   (memset 540704)
//   r @2736160:16 | wqs @2736176:64 | wks @2736240:64
//   E16 @2736304 (half): 4194304 halves = 2097152 slots; U2 (float) aliases
//     @2736304:4194304 after mfma_exps consumes E16 -> ends 6930608
//   Wo16T @6930608 (half): 524288 halves -> 7192752
//   WkT16 @7192752 (half): 32768 halves -> 7209136
//   expS @7209136 (half): 33554432 halves; Zst (float, 524288) aliases its
//     head after mfma_u2 reads expS
// ---------------------------------------------------------------------------
extern "C" void kernel_launch(void* const* d_in, const int* in_sizes, int n_in,
                              void* d_out, int out_size, void* d_ws, size_t ws_size,
                              hipStream_t stream)
{
    const float* emb = (const float*)d_in[0];
    const float* Wq  = (const float*)d_in[1];
    const float* Wk  = (const float*)d_in[2];
    const float* Wv  = (const float*)d_in[3];
    const float* Wo  = (const float*)d_in[4];
    float* out = (float*)d_out;
    float* ws  = (float*)d_ws;

    float* XT2   = ws;
    float* WkT   = ws + 2097152;
    float* WqT   = ws + 2129920;
    float* WvT   = ws + 2162688;
    float* G     = ws + 2195456;
    float* rs    = ws + 2719744;
    float* sums  = ws + 2727936;
    float* GW    = ws + 2727968;
    float* GQ    = ws + 2732064;
    float* r     = ws + 2736160;
    float* wqs   = ws + 2736176;
    float* wks   = ws + 2736240;
    __half* E16   = (__half*)(ws + 2736304);
    float* U2    = ws + 2736304;            // alias (E16 dead after mfma_exps)
    __half* Wo16T = (__half*)(ws + 6930608);
    __half* WkT16 = (__half*)(ws + 7192752);
    __half* expS  = (__half*)(ws + 7209136);
    float* Zst   = ws + 7209136;            // alias expS head (dead after mfma_u2)

    transpose_k<<<dim3(1, 32, 16), 256, 0, stream>>>(emb, XT2, 2048, 64, 64, 2048, 131072LL, 131072LL);
    transpose_k<<<dim3(8, 1, 1), 256, 0, stream>>>(Wk, WkT, 64, 512, 512, 64, 0, 0);
    transpose_k<<<dim3(8, 1, 1), 256, 0, stream>>>(Wq, WqT, 64, 512, 512, 64, 0, 0);
    transpose_k<<<dim3(8, 1, 1), 256, 0, stream>>>(Wv, WvT, 64, 512, 512, 64, 0, 0);
    hipMemsetAsync(G, 0, 540704 * sizeof(float), stream);  // G + rs + sums + GW + GQ
    wsum_k<<<2, 256, 0, stream>>>(Wq, Wk, wqs, wks);
    wk16_k<<<32, 256, 0, stream>>>(WkT, WkT16);

    // G[z=(d*8+b)*8+b'] = emb_q[d,b]^T @ emb_kv[d,b']   K=2048 split-K4
    gemm_tn<64, 64, 16, 4, 4, 4, float, float><<<dim3(1, 4, 128), 256, 0, stream>>>(
        emb, emb + 1048576, G, 2048, 64, 64, 64,
        8, 131072LL, 1, 0LL,
        64, -1048576LL, 8, 131072LL,
        1, 4096LL, 1, 0LL);

    // GW (z=0 from WkT) and GQ (z=1 from WqT): 64x64, K=512, split-K8 batched
    gemm_tn<64, 64, 16, 4, 4, 8, float, float><<<dim3(1, 8, 2), 256, 0, stream>>>(
        WkT, WkT, GW, 512, 64, 64, 64,
        1, 0LL, 2, 32768LL,
        1, 0LL, 2, 32768LL,
        1, 0LL, 2, 4096LL);

    stats2_k<<<128, 256, 0, stream>>>(G, GQ, GW, wqs, wks, sums);
    fin_k<<<1, 16, 0, stream>>>(sums, r);

    // E16[pair][i][c'] = sum_c Wq[c][i] * G[pair][c][c']   (fp16 out)
    gemm_tn<64, 64, 16, 4, 4, 1, float, __half><<<dim3(1, 8, 128), 256, 0, stream>>>(
        Wq, G, E16, 64, 512, 64, 64,
        1, 0LL, 1, 0LL,
        1, 4096LL, 1, 0LL,
        1, 32768LL, 1, 0LL);

    // expS = exp(r * E16 @ WkT16^T)  (MFMA f16), fused fp32 rowsums -> rs
    mfma_exps<<<dim3(4, 4, 128), 256, 0, stream>>>(E16, WkT16, r, expS, rs);

    // Wo16T[z][o][i] = fp16(Wo[i][o]*4096/rs[z][i])
    woprep_k<<<16, 256, 0, stream>>>(Wo, rs, Wo16T);

    // U2[z][j][o] = (1/4096) sum_i expS[i][j] * Wo16T[o][i]   (MFMA f16)
    mfma_u2<<<dim3(32, 1, 16), 256, 0, stream>>>(expS, Wo16T, U2);

    // Z[d,b,b'][c][o] = sum_ch WvT[ch][c] * U2[b'*512+ch][o]
    gemm_tn<64, 64, 16, 4, 4, 1, float, float><<<dim3(1, 1, 128), 256, 0, stream>>>(
        WvT, U2, Zst, 512, 64, 64, 64,
        1, 0LL, 1, 0LL,
        8, 262144LL, 8, 32768LL,
        1, 4096LL, 1, 0LL);

    // out[d*8+b][n][c] = sum_{b',c} XT2_kv[b'*64+c][n] * Zst[b'*64+c][o]
    gemm_tn<64, 64, 16, 4, 4, 1, float, float><<<dim3(1, 32, 16), 256, 0, stream>>>(
        XT2 + 1048576, Zst, out, 512, 2048, 64, 64,
        8, -1048576LL, 1, 0LL,
        1, 32768LL, 1, 0LL,
        1, 131072LL, 1, 0LL);
}